// Round 11
// baseline (288.639 us; speedup 1.0000x reference)
//
#include <hip/hip_runtime.h>
#include <hip/hip_bf16.h>

#define NN 10000
#define NE 160000
#define NGRP 625            // NN/16
#define XPLN 640000         // NN*64 elems per plane

#define SK_NORM   0.039528470752104741f   // 1/sqrt(640)
#define UP_NORM   0.125f                  // 1/8
#define M1_NORM   0.35355339059327373f    // 1/sqrt(8)
#define INV3      0.5773502691896258f
#define LIN_NORM  0.0027621358640099516f  // 1/sqrt(128)/32

__device__ __forceinline__ float siluf(float x) { return x / (1.0f + __expf(-x)); }

__device__ __forceinline__ unsigned short f2bf_bits(float x) {
    union { __hip_bfloat16 h; unsigned short u; } cv;
    cv.h = __float2bfloat16(x);
    return cv.u;
}
__device__ __forceinline__ float bflo(unsigned int w) { return __uint_as_float(w << 16); }
__device__ __forceinline__ float bfhi(unsigned int w) { return __uint_as_float(w & 0xffff0000u); }

typedef short bf16x8 __attribute__((ext_vector_type(8)));
typedef float f32x4  __attribute__((ext_vector_type(4)));

// ---------------- K0a: detect edge_index dtype (int64 vs int32).
__global__ __launch_bounds__(256) void k_detect(const int* __restrict__ ei32, int* __restrict__ flag) {
    __shared__ int cnt;
    if (threadIdx.x == 0) cnt = 0;
    __syncthreads();
    int z = 0;
    for (int i = threadIdx.x; i < 1024; i += 256)
        if (ei32[2 * i + 1] == 0) z++;
    atomicAdd(&cnt, z);
    __syncthreads();
    if (threadIdx.x == 0) flag[0] = (cnt >= 512) ? 1 : 0;
}

// ---------------- K0b: extract sender/receiver as int32 regardless of source dtype
__global__ __launch_bounds__(256) void k_cvt(const int* __restrict__ ei32, const int* __restrict__ flag,
                                             int* __restrict__ snd, int* __restrict__ rcv) {
    int e = blockIdx.x * 256 + threadIdx.x;
    if (e >= NE) return;
    if (flag[0]) {
        const long long* e64 = (const long long*)ei32;
        snd[e] = (int)e64[e];
        rcv[e] = (int)e64[NE + e];
    } else {
        snd[e] = ei32[e];
        rcv[e] = ei32[NE + e];
    }
}

// ---------------- K_wprepN: FRAGMENT-MAJOR node-side weight panels (WNF, 256KB).
__global__ __launch_bounds__(256) void k_wprepN(
    const float* __restrict__ Wsk_s, const float* __restrict__ Wsk_v,
    const float* __restrict__ Wu0, const float* __restrict__ Wu1,
    unsigned short* __restrict__ WNF) {
    int idx = blockIdx.x * 256 + threadIdx.x;
    if (idx >= 131072) return;
    float val;
    if (idx < 81920) {
        int p = idx / 10240, r = idx % 10240;
        int kc = r >> 9, l8 = r & 511;
        int lane = l8 >> 3, j = l8 & 7, quad = lane >> 4, lo = lane & 15;
        int a = kc >> 1, u = (kc & 1) * 32 + quad * 8 + j;
        val = Wsk_s[(u * 10 + a) * 128 + p * 16 + lo];
    } else if (idx < 122880) {
        int rel = idx - 81920;
        int p = rel / 10240, r = rel % 10240;
        int kc = r >> 9, l8 = r & 511;
        int lane = l8 >> 3, j = l8 & 7, quad = lane >> 4, lo = lane & 15;
        int a = kc >> 1, u = (kc & 1) * 32 + quad * 8 + j;
        val = Wsk_v[(u * 10 + a) * 64 + p * 16 + lo];
    } else if (idx < 126976) {
        int rel = idx - 122880;
        int p = rel >> 10, r = rel & 1023;
        int kc = r >> 9, l8 = r & 511;
        int lane = l8 >> 3, j = l8 & 7, quad = lane >> 4, lo = lane & 15;
        int u = kc * 32 + quad * 8 + j;
        val = Wu0[u * 64 + p * 16 + lo];
    } else {
        int rel = idx - 126976;
        int p = rel >> 10, r = rel & 1023;
        int kc = r >> 9, l8 = r & 511;
        int lane = l8 >> 3, j = l8 & 7, quad = lane >> 4, lo = lane & 15;
        int u = kc * 32 + quad * 8 + j;
        val = Wu1[u * 64 + p * 16 + lo];
    }
    WNF[idx] = f2bf_bits(val);
}

// ---------------- K_xprep: planar bf16 node features + transposed attrs.
__global__ __launch_bounds__(256) void k_xprep(
    const float* __restrict__ node_attrs, const float* __restrict__ node_feats,
    unsigned short* __restrict__ xpk, float* __restrict__ attrsP) {
    int idx = blockIdx.x * 256 + threadIdx.x;
    if (idx < 4 * NN * 64) {
        int n = idx >> 8, c = idx & 255;
        int plane = c >> 6, u = c & 63;
        float v = (plane == 0) ? node_feats[(long)n * 256 + u]
                               : node_feats[(long)n * 256 + 64 + u * 3 + (plane - 1)];
        xpk[(size_t)plane * XPLN + (long)n * 64 + u] = f2bf_bits(v);
        return;
    }
    int i2 = idx - 4 * NN * 64;
    if (i2 < 10 * NN) {
        int a = i2 / NN, n = i2 - a * NN;
        attrsP[i2] = node_attrs[(long)n * 10 + a];
    }
}

// ---------------- K_wprep2: FRAGMENT-MAJOR bf16 weights: edge MLP (WFG) + lin (WLF).
__global__ __launch_bounds__(256) void k_wprep2(
    const float* __restrict__ M1, const float* __restrict__ M2,
    const float* __restrict__ M3, const float* __restrict__ M4,
    const float* __restrict__ W_lin_s, const float* __restrict__ W_lin_v,
    unsigned short* __restrict__ WFG, unsigned short* __restrict__ WLF) {
    int idx = blockIdx.x * 256 + threadIdx.x;
    if (idx >= (52 + 48) * 512) return;
    if (idx < 52 * 512) {
        int f = idx >> 9, r = idx & 511;
        int lane = r >> 3, j = r & 7;
        int quad = lane >> 4, lo = lane & 15;
        float val;
        if (f < 4) {
            int n = f * 16 + lo, k = quad * 8 + j;
            val = (k < 8) ? M1[k * 64 + n] : 0.f;
        } else if (f < 12) {
            int g2 = f - 4, nt = g2 >> 1, half = g2 & 1;
            int n = nt * 16 + lo, k = half * 32 + quad * 8 + j;
            val = M2[k * 64 + n];
        } else if (f < 20) {
            int g3 = f - 12, nt = g3 >> 1, half = g3 & 1;
            int n = nt * 16 + lo, k = half * 32 + quad * 8 + j;
            val = M3[k * 64 + n];
        } else {
            int g4 = f - 20, tt = g4 >> 1, half = g4 & 1;
            int n = tt * 16 + lo, k = half * 32 + quad * 8 + j;
            val = M4[k * 256 + n];
        }
        WFG[idx] = f2bf_bits(val);
    } else {
        int rel = idx - 52 * 512;
        int f = rel >> 9, r = rel & 511;
        int lane = r >> 3, j = r & 7;
        int quad = lane >> 4, lo = lane & 15;
        float val;
        if (f < 32) {
            int vt = f >> 2, ks = f & 3;
            val = W_lin_s[(ks * 32 + quad * 8 + j) * 128 + vt * 16 + lo];
        } else {
            int f2 = f - 32;
            int vt = f2 >> 2, ks = f2 & 3;
            val = W_lin_v[(ks * 32 + quad * 8 + j) * 64 + vt * 16 + lo];
        }
        WLF[rel] = f2bf_bits(val);
    }
}

// ---------------- K_node v6: type-3 now writes PACKED x4 (float4 per channel).
// The same thread computes x0 and all 3 x1 planes for a channel -> pack them
// so k_conv does ONE dwordx4 gather per edge-lane instead of four dword
// gathers to 4 separate arrays (round-10 post-mortem: 4 address chains and
// 4 scattered 256B wave-regions were the latency bottleneck in k_conv).
#define G0 8
#define NB0 79
#define G2 4
#define NB2 157
#define G3 16
#define NB3 40
#define KNODE_GRID (4*NB0 + 2*NB2 + 2*NB3)   // 710

__global__ __launch_bounds__(128) void k_node(
    const unsigned short* __restrict__ xpk, const float* __restrict__ attrsP,
    const unsigned short* __restrict__ WNF,
    float* __restrict__ sc_s, float* __restrict__ sc_v,
    float4* __restrict__ x4) {
    __shared__ unsigned short pan[2 * 10240];
    __shared__ float att[10 * 128];

    int t = threadIdx.x;
    int bid = blockIdx.x;
    int type, vp, chunk;
    if (bid < 4 * NB0)                 { type = 0; vp = bid / NB0; chunk = bid % NB0; }
    else if (bid < 4 * NB0 + 2 * NB2)  { int r = bid - 4 * NB0; type = 2; vp = r / NB2; chunk = r % NB2; }
    else                               { int r = bid - 4 * NB0 - 2 * NB2; type = 3; vp = r / NB3; chunk = r % NB3; }
    int G = (type == 0) ? G0 : (type == 2 ? G2 : G3);
    int g0 = chunk * G;
    int ng = NGRP - g0; if (ng > G) ng = G;
    int n0 = g0 * 16;

    int psrc, pcnt;
    if (type == 0)      { psrc = vp * 2 * 10240;           pcnt = 20480; }
    else if (type == 2) { psrc = 81920 + vp * 2 * 10240;   pcnt = 20480; }
    else                { psrc = 122880 + vp * 2 * 1024;   pcnt = 2048;  }
    for (int i = t; i < pcnt / 8; i += 128)
        ((float4*)pan)[i] = ((const float4*)(WNF + psrc))[i];
    if (type == 3) {
        for (int i = t; i < 2048 / 8; i += 128)
            ((float4*)(pan + 2048))[i] = ((const float4*)(WNF + 126976 + vp * 2 * 1024))[i];
    }
    if (type <= 2) {
        int cnt = ng * 16;
        #pragma unroll
        for (int k = 0; k < 10; k++) {
            int i = k * 128 + t;
            int nl = t;
            if (nl < cnt) att[i] = attrsP[k * NN + n0 + nl];
        }
    }
    __syncthreads();

    int wv = t >> 6, lane = t & 63, lo = lane & 15, quad = lane >> 4;
    int lbase = lane * 8;
    const f32x4 zacc = {0.f, 0.f, 0.f, 0.f};
    const unsigned short* mypan = pan + wv * 10240;

    if (type == 0) {
        int vtg = vp * 2 + wv;
        const unsigned short* xb = xpk;
        bf16x8 nfa0 = *(const bf16x8*)(xb + (long)(n0 + lo) * 64 + quad * 8);
        bf16x8 nfa1 = *(const bf16x8*)(xb + (long)(n0 + lo) * 64 + 32 + quad * 8);
        #pragma unroll 1
        for (int g = 0; g < ng; g++) {
            bf16x8 fa0 = nfa0, fa1 = nfa1;
            if (g + 1 < ng) {
                nfa0 = *(const bf16x8*)(xb + (long)(n0 + (g + 1) * 16 + lo) * 64 + quad * 8);
                nfa1 = *(const bf16x8*)(xb + (long)(n0 + (g + 1) * 16 + lo) * 64 + 32 + quad * 8);
            }
            f32x4 acc = zacc;
            #pragma unroll
            for (int a = 0; a < 10; a++) {
                bf16x8 b0 = *(const bf16x8*)&mypan[(2 * a) * 512 + lbase];
                bf16x8 b1 = *(const bf16x8*)&mypan[(2 * a + 1) * 512 + lbase];
                f32x4 p = __builtin_amdgcn_mfma_f32_16x16x32_bf16(fa0, b0, zacc, 0, 0, 0);
                p = __builtin_amdgcn_mfma_f32_16x16x32_bf16(fa1, b1, p, 0, 0, 0);
                float4 afv = *(const float4*)&att[a * 128 + g * 16 + quad * 4];
                acc[0] += afv.x * p[0]; acc[1] += afv.y * p[1];
                acc[2] += afv.z * p[2]; acc[3] += afv.w * p[3];
            }
            int nb = n0 + g * 16;
            #pragma unroll
            for (int r = 0; r < 4; r++)
                sc_s[(long)(nb + quad * 4 + r) * 128 + vtg * 16 + lo] = acc[r] * SK_NORM;
        }
    } else if (type == 2) {
        int vt = vp * 2 + wv;
        bf16x8 nfa0[3], nfa1[3];
        #pragma unroll
        for (int i = 0; i < 3; i++) {
            const unsigned short* xb = xpk + (size_t)(1 + i) * XPLN + (long)(n0 + lo) * 64;
            nfa0[i] = *(const bf16x8*)(xb + quad * 8);
            nfa1[i] = *(const bf16x8*)(xb + 32 + quad * 8);
        }
        #pragma unroll 1
        for (int g = 0; g < ng; g++) {
            bf16x8 fa0[3], fa1[3];
            #pragma unroll
            for (int i = 0; i < 3; i++) { fa0[i] = nfa0[i]; fa1[i] = nfa1[i]; }
            if (g + 1 < ng) {
                #pragma unroll
                for (int i = 0; i < 3; i++) {
                    const unsigned short* xb = xpk + (size_t)(1 + i) * XPLN + (long)(n0 + (g + 1) * 16 + lo) * 64;
                    nfa0[i] = *(const bf16x8*)(xb + quad * 8);
                    nfa1[i] = *(const bf16x8*)(xb + 32 + quad * 8);
                }
            }
            f32x4 acc0 = zacc, acc1 = zacc, acc2 = zacc;
            #pragma unroll
            for (int a = 0; a < 10; a++) {
                bf16x8 b0 = *(const bf16x8*)&mypan[(2 * a) * 512 + lbase];
                bf16x8 b1 = *(const bf16x8*)&mypan[(2 * a + 1) * 512 + lbase];
                float4 afv = *(const float4*)&att[a * 128 + g * 16 + quad * 4];
                f32x4 p0 = __builtin_amdgcn_mfma_f32_16x16x32_bf16(fa0[0], b0, zacc, 0, 0, 0);
                p0 = __builtin_amdgcn_mfma_f32_16x16x32_bf16(fa1[0], b1, p0, 0, 0, 0);
                acc0[0] += afv.x * p0[0]; acc0[1] += afv.y * p0[1];
                acc0[2] += afv.z * p0[2]; acc0[3] += afv.w * p0[3];
                f32x4 p1 = __builtin_amdgcn_mfma_f32_16x16x32_bf16(fa0[1], b0, zacc, 0, 0, 0);
                p1 = __builtin_amdgcn_mfma_f32_16x16x32_bf16(fa1[1], b1, p1, 0, 0, 0);
                acc1[0] += afv.x * p1[0]; acc1[1] += afv.y * p1[1];
                acc1[2] += afv.z * p1[2]; acc1[3] += afv.w * p1[3];
                f32x4 p2 = __builtin_amdgcn_mfma_f32_16x16x32_bf16(fa0[2], b0, zacc, 0, 0, 0);
                p2 = __builtin_amdgcn_mfma_f32_16x16x32_bf16(fa1[2], b1, p2, 0, 0, 0);
                acc2[0] += afv.x * p2[0]; acc2[1] += afv.y * p2[1];
                acc2[2] += afv.z * p2[2]; acc2[3] += afv.w * p2[3];
            }
            int nb = n0 + g * 16;
            #pragma unroll
            for (int r = 0; r < 4; r++) {
                long rb = (long)(nb + quad * 4 + r) * 192 + vt * 16 + lo;
                sc_v[rb]       = acc0[r] * SK_NORM;
                sc_v[rb + 64]  = acc1[r] * SK_NORM;
                sc_v[rb + 128] = acc2[r] * SK_NORM;
            }
        }
    } else {
        int vt = vp * 2 + wv;
        bf16x8 bk20 = *(const bf16x8*)&pan[wv * 1024 + lbase];
        bf16x8 bk21 = *(const bf16x8*)&pan[wv * 1024 + 512 + lbase];
        bf16x8 bk30 = *(const bf16x8*)&pan[2048 + wv * 1024 + lbase];
        bf16x8 bk31 = *(const bf16x8*)&pan[2048 + wv * 1024 + 512 + lbase];
        #pragma unroll 1
        for (int g = 0; g < ng; g++) {
            int nb = n0 + g * 16;
            const unsigned short* xb0 = xpk + (long)(nb + lo) * 64;
            bf16x8 fa00 = *(const bf16x8*)(xb0 + quad * 8);
            bf16x8 fa01 = *(const bf16x8*)(xb0 + 32 + quad * 8);
            f32x4 acc0 = __builtin_amdgcn_mfma_f32_16x16x32_bf16(fa00, bk20, zacc, 0, 0, 0);
            acc0 = __builtin_amdgcn_mfma_f32_16x16x32_bf16(fa01, bk21, acc0, 0, 0, 0);
            const unsigned short* xb1 = xpk + (size_t)1 * XPLN + (long)(nb + lo) * 64;
            bf16x8 fa10 = *(const bf16x8*)(xb1 + quad * 8);
            bf16x8 fa11 = *(const bf16x8*)(xb1 + 32 + quad * 8);
            f32x4 acc1 = __builtin_amdgcn_mfma_f32_16x16x32_bf16(fa10, bk30, zacc, 0, 0, 0);
            acc1 = __builtin_amdgcn_mfma_f32_16x16x32_bf16(fa11, bk31, acc1, 0, 0, 0);
            const unsigned short* xb2 = xpk + (size_t)2 * XPLN + (long)(nb + lo) * 64;
            bf16x8 fa20 = *(const bf16x8*)(xb2 + quad * 8);
            bf16x8 fa21 = *(const bf16x8*)(xb2 + 32 + quad * 8);
            f32x4 acc2 = __builtin_amdgcn_mfma_f32_16x16x32_bf16(fa20, bk30, zacc, 0, 0, 0);
            acc2 = __builtin_amdgcn_mfma_f32_16x16x32_bf16(fa21, bk31, acc2, 0, 0, 0);
            const unsigned short* xb3 = xpk + (size_t)3 * XPLN + (long)(nb + lo) * 64;
            bf16x8 fa30 = *(const bf16x8*)(xb3 + quad * 8);
            bf16x8 fa31 = *(const bf16x8*)(xb3 + 32 + quad * 8);
            f32x4 acc3 = __builtin_amdgcn_mfma_f32_16x16x32_bf16(fa30, bk30, zacc, 0, 0, 0);
            acc3 = __builtin_amdgcn_mfma_f32_16x16x32_bf16(fa31, bk31, acc3, 0, 0, 0);
            #pragma unroll
            for (int r = 0; r < 4; r++) {
                x4[(long)(nb + quad * 4 + r) * 64 + vt * 16 + lo] =
                    make_float4(acc0[r] * UP_NORM, acc1[r] * UP_NORM,
                                acc2[r] * UP_NORM, acc3[r] * UP_NORM);
            }
        }
    }
}

// ---------------- K3: CSR build by receiver (epk = packed {sender, edge})
__global__ __launch_bounds__(256) void k_hist(const int* __restrict__ rcv, int* __restrict__ counts) {
    int e = blockIdx.x * 256 + threadIdx.x;
    if (e < NE) atomicAdd(&counts[rcv[e]], 1);
}

__global__ __launch_bounds__(1024) void k_scan(const int* __restrict__ counts, int* __restrict__ offsets) {
    __shared__ int partial[1024];
    int t = threadIdx.x;
    const int CHUNKS = (NN + 1023) / 1024;   // 10
    int base = t * CHUNKS;
    int s = 0;
    for (int i = 0; i < CHUNKS; i++) if (base + i < NN) s += counts[base + i];
    partial[t] = s;
    __syncthreads();
    for (int d = 1; d < 1024; d *= 2) {
        int v = (t >= d) ? partial[t - d] : 0;
        __syncthreads();
        partial[t] += v;
        __syncthreads();
    }
    int excl = (t == 0) ? 0 : partial[t - 1];
    for (int i = 0; i < CHUNKS; i++) {
        if (base + i < NN) { offsets[base + i] = excl; excl += counts[base + i]; }
    }
    if (t == 1023) offsets[NN] = partial[1023];
}

__global__ __launch_bounds__(256) void k_fill(const int* __restrict__ rcv, const int* __restrict__ snd,
                                              const int* __restrict__ offsets,
                                              int* __restrict__ cursor, int2* __restrict__ epk) {
    int e = blockIdx.x * 256 + threadIdx.x;
    if (e < NE) {
        int r = rcv[e];
        int pos = atomicAdd(&cursor[r], 1);
        epk[offsets[r] + pos] = make_int2(snd[e], e);
    }
}

// ---------------- K_eprep: CSR-ordered edge streams
__global__ __launch_bounds__(256) void k_eprep(const int2* __restrict__ epk,
                                               const float4* __restrict__ ear, const float4* __restrict__ eai,
                                               const float4* __restrict__ ef,
                                               int* __restrict__ sndp,
                                               float4* __restrict__ earp, float4* __restrict__ eaip,
                                               float4* __restrict__ efp) {
    int j = blockIdx.x * 256 + threadIdx.x;
    if (j >= NE) return;
    int2 se = epk[j];
    sndp[j] = se.x;
    earp[j] = ear[se.y];
    eaip[j] = eai[se.y];
    efp[(long)j * 2]     = ef[(long)se.y * 2];
    efp[(long)j * 2 + 1] = ef[(long)se.y * 2 + 1];
}

// ---------------- K2 v4: edge MLP via MFMA — occupancy unlocked (round-10, kept).
#define HID_STRIDE 72
#define OB_STRIDE  40
#define EPB 64

__global__ __launch_bounds__(256) void k_edge_mlp(
    const float4* __restrict__ efp, const unsigned short* __restrict__ WFG,
    __hip_bfloat16* __restrict__ twp) {
    __shared__ unsigned short wfrag[20 * 512];          // 20480 B (L1-L3 only)
    __shared__ unsigned short hid[4][16 * HID_STRIDE];  //  9216 B

    int t = threadIdx.x;
    for (int i = t; i < 20 * 512 / 8; i += 256)
        ((float4*)wfrag)[i] = ((const float4*)WFG)[i];
    __syncthreads();

    int wv = t >> 6;
    int lane = t & 63;
    int lo = lane & 15;
    int quad = lane >> 4;
    int lbase = lane * 8;
    unsigned short* myhid = hid[wv];
    unsigned short* myob  = hid[wv];    // alias; safe per-wave in-order DS
    const unsigned short* W4 = WFG + 20 * 512;   // M4 frags from global/L2
    const f32x4 zacc = {0.f, 0.f, 0.f, 0.f};

    long jbase = (long)blockIdx.x * EPB + wv * 16;

    // ---- layer 1: [16x8] @ [8x64] (K padded to 32), silu ----
    bf16x8 a1 = {0, 0, 0, 0, 0, 0, 0, 0};
    if (quad == 0) {
        float4 f0 = efp[(jbase + lo) * 2];
        float4 f1 = efp[(jbase + lo) * 2 + 1];
        union { unsigned short us[8]; bf16x8 v; } pk;
        pk.us[0] = f2bf_bits(f0.x * M1_NORM); pk.us[1] = f2bf_bits(f0.y * M1_NORM);
        pk.us[2] = f2bf_bits(f0.z * M1_NORM); pk.us[3] = f2bf_bits(f0.w * M1_NORM);
        pk.us[4] = f2bf_bits(f1.x * M1_NORM); pk.us[5] = f2bf_bits(f1.y * M1_NORM);
        pk.us[6] = f2bf_bits(f1.z * M1_NORM); pk.us[7] = f2bf_bits(f1.w * M1_NORM);
        a1 = pk.v;
    }
    {
        f32x4 acc[4];
        #pragma unroll
        for (int nt = 0; nt < 4; nt++) {
            bf16x8 b = *(const bf16x8*)&wfrag[nt * 512 + lbase];
            acc[nt] = __builtin_amdgcn_mfma_f32_16x16x32_bf16(a1, b, zacc, 0, 0, 0);
        }
        #pragma unroll
        for (int nt = 0; nt < 4; nt++)
            #pragma unroll
            for (int r = 0; r < 4; r++)
                myhid[(quad * 4 + r) * HID_STRIDE + nt * 16 + lo] = f2bf_bits(siluf(acc[nt][r]));
    }

    // ---- layers 2,3: [16x64] @ [64x64] /8, silu ----
    #pragma unroll
    for (int L = 0; L < 2; L++) {
        int fb = 4 + L * 8;
        bf16x8 a0 = *(const bf16x8*)&myhid[lo * HID_STRIDE + quad * 8];
        bf16x8 a1v = *(const bf16x8*)&myhid[lo * HID_STRIDE + 32 + quad * 8];
        f32x4 acc[4];
        #pragma unroll
        for (int nt = 0; nt < 4; nt++) {
            bf16x8 b0 = *(const bf16x8*)&wfrag[(fb + nt * 2) * 512 + lbase];
            bf16x8 b1 = *(const bf16x8*)&wfrag[(fb + nt * 2 + 1) * 512 + lbase];
            acc[nt] = __builtin_amdgcn_mfma_f32_16x16x32_bf16(a0, b0, zacc, 0, 0, 0);
            acc[nt] = __builtin_amdgcn_mfma_f32_16x16x32_bf16(a1v, b1, acc[nt], 0, 0, 0);
        }
        #pragma unroll
        for (int nt = 0; nt < 4; nt++)
            #pragma unroll
            for (int r = 0; r < 4; r++)
                myhid[(quad * 4 + r) * HID_STRIDE + nt * 16 + lo] = f2bf_bits(siluf(acc[nt][r] * 0.125f));
    }

    // ---- layer 4: [16x64] @ [64x256] /8, pair output, 16B LDS-shuffled stores ----
    {
        bf16x8 a0 = *(const bf16x8*)&myhid[lo * HID_STRIDE + quad * 8];
        bf16x8 a1v = *(const bf16x8*)&myhid[lo * HID_STRIDE + 32 + quad * 8];
        int sedge = lane >> 2, sch = lane & 3;
        #pragma unroll
        for (int rd = 0; rd < 8; rd++) {
            f32x4 acc2[2];
            #pragma unroll
            for (int p = 0; p < 2; p++) {
                int tt = (rd < 4) ? (p * 4 + rd) : (8 + p * 4 + (rd - 4));
                bf16x8 b0 = *(const bf16x8*)(W4 + (tt * 2) * 512 + lbase);
                bf16x8 b1 = *(const bf16x8*)(W4 + (tt * 2 + 1) * 512 + lbase);
                acc2[p] = __builtin_amdgcn_mfma_f32_16x16x32_bf16(a0, b0, zacc, 0, 0, 0);
                acc2[p] = __builtin_amdgcn_mfma_f32_16x16x32_bf16(a1v, b1, acc2[p], 0, 0, 0);
            }
            #pragma unroll
            for (int p = 0; p < 2; p++)
                #pragma unroll
                for (int r = 0; r < 4; r++)
                    myob[(quad * 4 + r) * OB_STRIDE + 2 * lo + p] = f2bf_bits(acc2[p][r] * 0.125f);
            bf16x8 vv = *(const bf16x8*)&myob[sedge * OB_STRIDE + sch * 8];
            *(bf16x8*)(twp + (jbase + sedge) * 256 + rd * 32 + sch * 8) = vv;
        }
    }
}

// ---------------- K4 v6: conv_tp + segment sum -> msgF.
// Round-10 post-mortem: 47us, 4 separate x-gathers per edge-lane (4 address
// chains, 4 scattered 256B wave-regions) were the latency bottleneck. v6:
// k_node packs {x0, x1_0, x1_1, x1_2} as ONE float4 per (node,channel) ->
// one dwordx4 gather per edge-lane; freed VGPRs raise CB2 4->8 (gather
// latency rounds 4->2). Accumulation order per node unchanged (j-increasing)
// -> bit-identical msgF.
#define NPB 4
#define CB2 8
__global__ __launch_bounds__(256) void k_conv(
    const int* __restrict__ offsets, const int* __restrict__ sndp,
    const float4* __restrict__ earp, const float4* __restrict__ eaip,
    const float4* __restrict__ x4,
    const __hip_bfloat16* __restrict__ twp,
    unsigned short* __restrict__ msgF) {
    __shared__ unsigned short stg[NPB][1024];
    int t = threadIdx.x;
    int wv = t >> 6;
    int u = t & 63;
    int n = blockIdx.x * NPB + wv;
    int beg = offsets[n], end = offsets[n + 1];
    int deg = end - beg;
    int sreg = (u < deg) ? sndp[beg + u] : 0;   // lane-parallel senders
    const int tsel0 = 2 * u, tsel1 = 128 + 2 * u;
    float a0r = 0.f, a1r = 0.f, a2r = 0.f, a3r = 0.f;
    float a0i = 0.f, a1i = 0.f, a2i = 0.f, a3i = 0.f;
    float c0r = 0.f, c1r = 0.f, c2r = 0.f, c3r = 0.f;
    float c0i = 0.f, c1i = 0.f, c2i = 0.f, c3i = 0.f;

    for (int jb = beg; jb < end; jb += CB2) {
        unsigned int t0[CB2], t1[CB2];
        float4 xv[CB2], yr[CB2], yi[CB2];
        #pragma unroll
        for (int p = 0; p < CB2; p++) {
            int j = jb + p;
            int jc = (j < end) ? j : (end - 1);
            int le = jc - beg;
            int s = (le < 64) ? __shfl(sreg, le) : sndp[jc];
            yr[p] = earp[jc];
            yi[p] = eaip[jc];
            xv[p] = x4[(long)s * 64 + u];
            bool valid = (j < end);
            t0[p] = valid ? *(const unsigned int*)(twp + (long)jc * 256 + tsel0) : 0u;
            t1[p] = valid ? *(const unsigned int*)(twp + (long)jc * 256 + tsel1) : 0u;
        }
        #pragma unroll
        for (int p = 0; p < CB2; p++) {
            float wA = bflo(t0[p]), wB = bfhi(t0[p]);
            float xa = xv[p].x * wA, xb = xv[p].x * wB;
            a0r += xa * yr[p].x; a1r += xb * yr[p].y; a2r += xb * yr[p].z; a3r += xb * yr[p].w;
            a0i += xa * yi[p].x; a1i += xb * yi[p].y; a2i += xb * yi[p].z; a3i += xb * yi[p].w;
            float wC = bflo(t1[p]), wDs = bfhi(t1[p]) * INV3;
            float dr = xv[p].y * yr[p].y + xv[p].z * yr[p].z + xv[p].w * yr[p].w;
            float di = xv[p].y * yi[p].y + xv[p].z * yi[p].z + xv[p].w * yi[p].w;
            c0r += dr * wDs; c0i += di * wDs;
            float ycr = yr[p].x * wC, yci = yi[p].x * wC;
            c1r += xv[p].y * ycr; c2r += xv[p].z * ycr; c3r += xv[p].w * ycr;
            c1i += xv[p].y * yci; c2i += xv[p].z * yci; c3i += xv[p].w * yci;
        }
    }

    unsigned short* sg = stg[wv];
    sg[u]       = f2bf_bits(a0r);
    sg[128 + u] = f2bf_bits(a0i);
    sg[256 + u] = f2bf_bits(a1r);
    sg[384 + u] = f2bf_bits(a2r);
    sg[512 + u] = f2bf_bits(a3r);
    sg[640 + u] = f2bf_bits(a1i);
    sg[768 + u] = f2bf_bits(a2i);
    sg[896 + u] = f2bf_bits(a3i);
    sg[64 + u]  = f2bf_bits(c0r);
    sg[192 + u] = f2bf_bits(c0i);
    sg[320 + u] = f2bf_bits(c1r);
    sg[448 + u] = f2bf_bits(c2r);
    sg[576 + u] = f2bf_bits(c3r);
    sg[704 + u] = f2bf_bits(c1i);
    sg[832 + u] = f2bf_bits(c2i);
    sg[960 + u] = f2bf_bits(c3i);
    __syncthreads();

    #pragma unroll
    for (int rep = 0; rep < 2; rep++) {
        int job = rep * 256 + t;
        int m = job >> 7, c = job & 127;
        int nm = blockIdx.x * NPB + m;
        int g = nm >> 4, lo = nm & 15;
        bf16x8 vv = *(const bf16x8*)&stg[m][c * 8];
        *(bf16x8*)(msgF + (size_t)g * 16384 + (c >> 2) * 512 + lo * 32 + (c & 3) * 8) = vv;
    }
}

// ---------------- K5 v2: MFMA lin + skip + gate, fragment-major (unchanged).
#define SV_STRIDE 129
#define VV_STRIDE 65

__global__ __launch_bounds__(256, 3) void k_lin(
    const unsigned short* __restrict__ msgF,
    const float* __restrict__ sc_s, const float* __restrict__ sc_v,
    const unsigned short* __restrict__ WLF,
    float* __restrict__ out) {
    __shared__ char smem[49152];
    unsigned short* wfrag = (unsigned short*)smem;
    float* sval = (float*)smem;                       // aliased after barrier
    float* vval = (float*)(smem + 2 * 16 * SV_STRIDE * 4);

    int t = threadIdx.x;
    for (int i = t; i < 48 * 512 / 8; i += 256)
        ((float4*)wfrag)[i] = ((const float4*)WLF)[i];
    __syncthreads();

    int wv = t >> 6;
    int lane = t & 63;
    int lo = lane & 15;
    int quad = lane >> 4;
    int lbase = lane * 8;
    int aoff_lane = lo * 32 + quad * 8;
    const f32x4 zacc = {0.f, 0.f, 0.f, 0.f};

    long g = blockIdx.x;
    long nbase = g * 16;
    const unsigned short* agbase = msgF + (size_t)g * 16384;

    f32x4 accs[10];
    #pragma unroll
    for (int q = 0; q < 10; q++) {
        int tau = wv + q * 4;
        int cblk, fb;
        if (tau < 16) {
            int ri = tau >> 3, vt = tau & 7;
            cblk = ri; fb = vt * 4;
        } else {
            int tp = tau - 16;
            int ri = tp / 12, rem = tp % 12;
            int i = rem >> 2, vt = rem & 3;
            cblk = 2 + ri * 3 + i; fb = 32 + vt * 4;
        }
        f32x4 acc = zacc;
        #pragma unroll
        for (int ks = 0; ks < 4; ks++) {
            bf16x8 a = *(const bf16x8*)(agbase + (cblk * 4 + ks) * 512 + aoff_lane);
            bf16x8 b = *(const bf16x8*)&wfrag[(fb + ks) * 512 + lbase];
            acc = __builtin_amdgcn_mfma_f32_16x16x32_bf16(a, b, acc, 0, 0, 0);
        }
        accs[q] = acc;
    }
    __syncthreads();   // all weight LDS reads complete before aliasing

    #pragma unroll
    for (int q = 0; q < 10; q++) {
        int tau = wv + q * 4;
        if (tau < 16) {
            int ri = tau >> 3, vt = tau & 7;
            int cidx = (ri * 16) * SV_STRIDE + vt * 16 + lo;
            #pragma unroll
            for (int r = 0; r < 4; r++)
                sval[cidx + (quad * 4 + r) * SV_STRIDE] = accs[q][r] * LIN_NORM;
        } else {
            int tp = tau - 16;
            int ri = tp / 12, rem = tp % 12;
            int i = rem >> 2, vt = rem & 3;
            int cidx = ((ri * 3 + i) * 16) * VV_STRIDE + vt * 16 + lo;
            #pragma unroll
            for (int r = 0; r < 4; r++)
                vval[cidx + (quad * 4 + r) * VV_STRIDE] = accs[q][r] * LIN_NORM;
        }
    }
    __syncthreads();

    #pragma unroll 1
    for (int j = 0; j < 16; j++) {
        int c = t;
        long gn = nbase + j;
        float re, im;
        if (c < 64) {
            float sr = sval[(0 * 16 + j) * SV_STRIDE + c] + sc_s[gn * 128 + c];
            float si = sval[(1 * 16 + j) * SV_STRIDE + c];
            re = siluf(sr); im = siluf(si);
        } else {
            int rem = c - 64;
            int v = rem / 3;
            int i = rem - v * 3;
            float gr = siluf(sval[(0 * 16 + j) * SV_STRIDE + 64 + v] + sc_s[gn * 128 + 64 + v]);
            float gi = siluf(sval[(1 * 16 + j) * SV_STRIDE + 64 + v]);
            float lr = vval[((0 * 3 + i) * 16 + j) * VV_STRIDE + v] + sc_v[gn * 192 + i * 64 + v];
            float li = vval[((1 * 3 + i) * 16 + j) * VV_STRIDE + v];
            re = lr * gr; im = li * gi;
        }
        ((float2*)out)[gn * 256 + c] = make_float2(re, im);
    }
}

extern "C" void kernel_launch(void* const* d_in, const int* in_sizes, int n_in,
                              void* d_out, int out_size, void* d_ws, size_t ws_size,
                              hipStream_t stream) {
    const float* node_attrs = (const float*)d_in[0];
    const float* node_feats = (const float*)d_in[1];
    const float* ear        = (const float*)d_in[2];
    const float* eai        = (const float*)d_in[3];
    const float* edge_feats = (const float*)d_in[4];
    const float* W_up0      = (const float*)d_in[5];
    const float* W_up1      = (const float*)d_in[6];
    const float* M1         = (const float*)d_in[7];
    const float* M2         = (const float*)d_in[8];
    const float* M3         = (const float*)d_in[9];
    const float* M4         = (const float*)d_in[10];
    const float* W_lin_s    = (const float*)d_in[11];
    const float* W_lin_v    = (const float*)d_in[12];
    const float* W_sk_s     = (const float*)d_in[13];
    const float* W_sk_v     = (const float*)d_in[14];
    const int*   ei         = (const int*)d_in[15];

    char* ws = (char*)d_ws;
    size_t o_x4  = 0;                                   // packed x: NN*64 float4 (10.24MB)
    size_t o_scs = o_x4 + (size_t)NN * 64 * 16;
    size_t o_scv = o_scs + (size_t)NN * 128 * 4;
    size_t o_tw  = o_scv + (size_t)NN * 192 * 4;
    size_t o_cnt = o_tw  + (size_t)NE * 256 * 2;
    size_t o_cur = o_cnt + (size_t)NN * 4;
    size_t o_ofs = o_cur + (size_t)NN * 4;
    size_t o_epk = o_ofs + (size_t)(NN + 1) * 4 + 60;
    size_t o_snd = o_epk + (size_t)NE * 8;
    size_t o_rcv = o_snd + (size_t)NE * 4;
    size_t o_flg = o_rcv + (size_t)NE * 4;
    size_t o_msg = o_flg + 64;
    size_t o_wnf = o_msg + (size_t)NN * 1024 * 2;
    size_t o_snp = o_wnf + 262144;
    size_t o_erp = o_snp + (size_t)NE * 4;
    size_t o_eip = o_erp + (size_t)NE * 16;
    size_t o_efp = o_eip + (size_t)NE * 16;
    size_t o_wfg = o_efp + (size_t)NE * 32;
    size_t o_wlf = o_wfg + (size_t)52 * 512 * 2;
    size_t o_xpk = o_wlf + (size_t)48 * 512 * 2;
    size_t o_atp = o_xpk + (size_t)4 * NN * 64 * 2;

    float4* x4 = (float4*)(ws + o_x4);
    float* sc_s = (float*)(ws + o_scs);
    float* sc_v = (float*)(ws + o_scv);
    __hip_bfloat16* twp = (__hip_bfloat16*)(ws + o_tw);
    int* counts  = (int*)(ws + o_cnt);
    int* cursor  = (int*)(ws + o_cur);
    int* offsets = (int*)(ws + o_ofs);
    int2* epk    = (int2*)(ws + o_epk);
    int* snd     = (int*)(ws + o_snd);
    int* rcv     = (int*)(ws + o_rcv);
    int* flag    = (int*)(ws + o_flg);
    unsigned short* msgF = (unsigned short*)(ws + o_msg);
    unsigned short* WNF = (unsigned short*)(ws + o_wnf);
    int*    sndp = (int*)(ws + o_snp);
    float4* earp = (float4*)(ws + o_erp);
    float4* eaip = (float4*)(ws + o_eip);
    float4* efp  = (float4*)(ws + o_efp);
    unsigned short* WFG = (unsigned short*)(ws + o_wfg);
    unsigned short* WLF = (unsigned short*)(ws + o_wlf);
    unsigned short* xpk = (unsigned short*)(ws + o_xpk);
    float* attrsP = (float*)(ws + o_atp);

    hipMemsetAsync(ws + o_cnt, 0, (size_t)NN * 8, stream);

    dim3 b256(256), b1024(1024), b128(128);
    k_detect<<<dim3(1), b256, 0, stream>>>(ei, flag);
    k_cvt   <<<dim3((NE + 255) / 256), b256, 0, stream>>>(ei, flag, snd, rcv);
    k_hist<<<dim3((NE + 255) / 256), b256, 0, stream>>>(rcv, counts);
    k_scan<<<dim3(1), b1024, 0, stream>>>(counts, offsets);
    k_fill<<<dim3((NE + 255) / 256), b256, 0, stream>>>(rcv, snd, offsets, cursor, epk);
    k_eprep<<<dim3((NE + 255) / 256), b256, 0, stream>>>(epk, (const float4*)ear, (const float4*)eai,
                                                         (const float4*)edge_feats,
                                                         sndp, earp, eaip, efp);
    k_wprepN<<<dim3(512), b256, 0, stream>>>(W_sk_s, W_sk_v, W_up0, W_up1, WNF);
    k_wprep2<<<dim3(200), b256, 0, stream>>>(M1, M2, M3, M4, W_lin_s, W_lin_v, WFG, WLF);
    k_xprep <<<dim3((4 * NN * 64 + 10 * NN + 255) / 256), b256, 0, stream>>>(node_attrs, node_feats, xpk, attrsP);
    k_node  <<<dim3(KNODE_GRID), b128, 0, stream>>>(xpk, attrsP, WNF, sc_s, sc_v, x4);
    k_edge_mlp<<<dim3(NE / EPB), b256, 0, stream>>>(efp, WFG, twp);
    k_conv<<<dim3(NN / NPB), b256, 0, stream>>>(offsets, sndp, earp, eaip, x4, twp, msgF);
    k_lin <<<dim3(NGRP), b256, 0, stream>>>(msgF, sc_s, sc_v, WLF, (float*)d_out);
}

// Round 12
// 267.374 us; speedup vs baseline: 1.0795x; 1.0795x over previous
//
#include <hip/hip_runtime.h>
#include <hip/hip_bf16.h>

#define NN 10000
#define NE 160000
#define NGRP 625            // NN/16
#define XPLN 640000         // NN*64 elems per plane

#define SK_NORM   0.039528470752104741f   // 1/sqrt(640)
#define UP_NORM   0.125f                  // 1/8
#define M1_NORM   0.35355339059327373f    // 1/sqrt(8)
#define INV3      0.5773502691896258f
#define LIN_NORM  0.0027621358640099516f  // 1/sqrt(128)/32

__device__ __forceinline__ float siluf(float x) { return x / (1.0f + __expf(-x)); }

__device__ __forceinline__ unsigned short f2bf_bits(float x) {
    union { __hip_bfloat16 h; unsigned short u; } cv;
    cv.h = __float2bfloat16(x);
    return cv.u;
}
__device__ __forceinline__ float bflo(unsigned int w) { return __uint_as_float(w << 16); }
__device__ __forceinline__ float bfhi(unsigned int w) { return __uint_as_float(w & 0xffff0000u); }

typedef short bf16x8 __attribute__((ext_vector_type(8)));
typedef float f32x4  __attribute__((ext_vector_type(4)));

// ---------------- K0a: detect edge_index dtype (int64 vs int32).
__global__ __launch_bounds__(256) void k_detect(const int* __restrict__ ei32, int* __restrict__ flag) {
    __shared__ int cnt;
    if (threadIdx.x == 0) cnt = 0;
    __syncthreads();
    int z = 0;
    for (int i = threadIdx.x; i < 1024; i += 256)
        if (ei32[2 * i + 1] == 0) z++;
    atomicAdd(&cnt, z);
    __syncthreads();
    if (threadIdx.x == 0) flag[0] = (cnt >= 512) ? 1 : 0;
}

// ---------------- K0b: extract sender/receiver as int32 regardless of source dtype
__global__ __launch_bounds__(256) void k_cvt(const int* __restrict__ ei32, const int* __restrict__ flag,
                                             int* __restrict__ snd, int* __restrict__ rcv) {
    int e = blockIdx.x * 256 + threadIdx.x;
    if (e >= NE) return;
    if (flag[0]) {
        const long long* e64 = (const long long*)ei32;
        snd[e] = (int)e64[e];
        rcv[e] = (int)e64[NE + e];
    } else {
        snd[e] = ei32[e];
        rcv[e] = ei32[NE + e];
    }
}

// ---------------- K_wprepN: FRAGMENT-MAJOR node-side weight panels (WNF, 256KB).
__global__ __launch_bounds__(256) void k_wprepN(
    const float* __restrict__ Wsk_s, const float* __restrict__ Wsk_v,
    const float* __restrict__ Wu0, const float* __restrict__ Wu1,
    unsigned short* __restrict__ WNF) {
    int idx = blockIdx.x * 256 + threadIdx.x;
    if (idx >= 131072) return;
    float val;
    if (idx < 81920) {
        int p = idx / 10240, r = idx % 10240;
        int kc = r >> 9, l8 = r & 511;
        int lane = l8 >> 3, j = l8 & 7, quad = lane >> 4, lo = lane & 15;
        int a = kc >> 1, u = (kc & 1) * 32 + quad * 8 + j;
        val = Wsk_s[(u * 10 + a) * 128 + p * 16 + lo];
    } else if (idx < 122880) {
        int rel = idx - 81920;
        int p = rel / 10240, r = rel % 10240;
        int kc = r >> 9, l8 = r & 511;
        int lane = l8 >> 3, j = l8 & 7, quad = lane >> 4, lo = lane & 15;
        int a = kc >> 1, u = (kc & 1) * 32 + quad * 8 + j;
        val = Wsk_v[(u * 10 + a) * 64 + p * 16 + lo];
    } else if (idx < 126976) {
        int rel = idx - 122880;
        int p = rel >> 10, r = rel & 1023;
        int kc = r >> 9, l8 = r & 511;
        int lane = l8 >> 3, j = l8 & 7, quad = lane >> 4, lo = lane & 15;
        int u = kc * 32 + quad * 8 + j;
        val = Wu0[u * 64 + p * 16 + lo];
    } else {
        int rel = idx - 126976;
        int p = rel >> 10, r = rel & 1023;
        int kc = r >> 9, l8 = r & 511;
        int lane = l8 >> 3, j = l8 & 7, quad = lane >> 4, lo = lane & 15;
        int u = kc * 32 + quad * 8 + j;
        val = Wu1[u * 64 + p * 16 + lo];
    }
    WNF[idx] = f2bf_bits(val);
}

// ---------------- K_xprep: planar bf16 node features + transposed attrs.
__global__ __launch_bounds__(256) void k_xprep(
    const float* __restrict__ node_attrs, const float* __restrict__ node_feats,
    unsigned short* __restrict__ xpk, float* __restrict__ attrsP) {
    int idx = blockIdx.x * 256 + threadIdx.x;
    if (idx < 4 * NN * 64) {
        int n = idx >> 8, c = idx & 255;
        int plane = c >> 6, u = c & 63;
        float v = (plane == 0) ? node_feats[(long)n * 256 + u]
                               : node_feats[(long)n * 256 + 64 + u * 3 + (plane - 1)];
        xpk[(size_t)plane * XPLN + (long)n * 64 + u] = f2bf_bits(v);
        return;
    }
    int i2 = idx - 4 * NN * 64;
    if (i2 < 10 * NN) {
        int a = i2 / NN, n = i2 - a * NN;
        attrsP[i2] = node_attrs[(long)n * 10 + a];
    }
}

// ---------------- K_wprep2: FRAGMENT-MAJOR bf16 weights: edge MLP (WFG) + lin (WLF).
__global__ __launch_bounds__(256) void k_wprep2(
    const float* __restrict__ M1, const float* __restrict__ M2,
    const float* __restrict__ M3, const float* __restrict__ M4,
    const float* __restrict__ W_lin_s, const float* __restrict__ W_lin_v,
    unsigned short* __restrict__ WFG, unsigned short* __restrict__ WLF) {
    int idx = blockIdx.x * 256 + threadIdx.x;
    if (idx >= (52 + 48) * 512) return;
    if (idx < 52 * 512) {
        int f = idx >> 9, r = idx & 511;
        int lane = r >> 3, j = r & 7;
        int quad = lane >> 4, lo = lane & 15;
        float val;
        if (f < 4) {
            int n = f * 16 + lo, k = quad * 8 + j;
            val = (k < 8) ? M1[k * 64 + n] : 0.f;
        } else if (f < 12) {
            int g2 = f - 4, nt = g2 >> 1, half = g2 & 1;
            int n = nt * 16 + lo, k = half * 32 + quad * 8 + j;
            val = M2[k * 64 + n];
        } else if (f < 20) {
            int g3 = f - 12, nt = g3 >> 1, half = g3 & 1;
            int n = nt * 16 + lo, k = half * 32 + quad * 8 + j;
            val = M3[k * 64 + n];
        } else {
            int g4 = f - 20, tt = g4 >> 1, half = g4 & 1;
            int n = tt * 16 + lo, k = half * 32 + quad * 8 + j;
            val = M4[k * 256 + n];
        }
        WFG[idx] = f2bf_bits(val);
    } else {
        int rel = idx - 52 * 512;
        int f = rel >> 9, r = rel & 511;
        int lane = r >> 3, j = r & 7;
        int quad = lane >> 4, lo = lane & 15;
        float val;
        if (f < 32) {
            int vt = f >> 2, ks = f & 3;
            val = W_lin_s[(ks * 32 + quad * 8 + j) * 128 + vt * 16 + lo];
        } else {
            int f2 = f - 32;
            int vt = f2 >> 2, ks = f2 & 3;
            val = W_lin_v[(ks * 32 + quad * 8 + j) * 64 + vt * 16 + lo];
        }
        WLF[rel] = f2bf_bits(val);
    }
}

// ---------------- K_node v6: type-3 writes PACKED x4 (float4 per channel; kept).
#define G0 8
#define NB0 79
#define G2 4
#define NB2 157
#define G3 16
#define NB3 40
#define KNODE_GRID (4*NB0 + 2*NB2 + 2*NB3)   // 710

__global__ __launch_bounds__(128) void k_node(
    const unsigned short* __restrict__ xpk, const float* __restrict__ attrsP,
    const unsigned short* __restrict__ WNF,
    float* __restrict__ sc_s, float* __restrict__ sc_v,
    float4* __restrict__ x4) {
    __shared__ unsigned short pan[2 * 10240];
    __shared__ float att[10 * 128];

    int t = threadIdx.x;
    int bid = blockIdx.x;
    int type, vp, chunk;
    if (bid < 4 * NB0)                 { type = 0; vp = bid / NB0; chunk = bid % NB0; }
    else if (bid < 4 * NB0 + 2 * NB2)  { int r = bid - 4 * NB0; type = 2; vp = r / NB2; chunk = r % NB2; }
    else                               { int r = bid - 4 * NB0 - 2 * NB2; type = 3; vp = r / NB3; chunk = r % NB3; }
    int G = (type == 0) ? G0 : (type == 2 ? G2 : G3);
    int g0 = chunk * G;
    int ng = NGRP - g0; if (ng > G) ng = G;
    int n0 = g0 * 16;

    int psrc, pcnt;
    if (type == 0)      { psrc = vp * 2 * 10240;           pcnt = 20480; }
    else if (type == 2) { psrc = 81920 + vp * 2 * 10240;   pcnt = 20480; }
    else                { psrc = 122880 + vp * 2 * 1024;   pcnt = 2048;  }
    for (int i = t; i < pcnt / 8; i += 128)
        ((float4*)pan)[i] = ((const float4*)(WNF + psrc))[i];
    if (type == 3) {
        for (int i = t; i < 2048 / 8; i += 128)
            ((float4*)(pan + 2048))[i] = ((const float4*)(WNF + 126976 + vp * 2 * 1024))[i];
    }
    if (type <= 2) {
        int cnt = ng * 16;
        #pragma unroll
        for (int k = 0; k < 10; k++) {
            int i = k * 128 + t;
            int nl = t;
            if (nl < cnt) att[i] = attrsP[k * NN + n0 + nl];
        }
    }
    __syncthreads();

    int wv = t >> 6, lane = t & 63, lo = lane & 15, quad = lane >> 4;
    int lbase = lane * 8;
    const f32x4 zacc = {0.f, 0.f, 0.f, 0.f};
    const unsigned short* mypan = pan + wv * 10240;

    if (type == 0) {
        int vtg = vp * 2 + wv;
        const unsigned short* xb = xpk;
        bf16x8 nfa0 = *(const bf16x8*)(xb + (long)(n0 + lo) * 64 + quad * 8);
        bf16x8 nfa1 = *(const bf16x8*)(xb + (long)(n0 + lo) * 64 + 32 + quad * 8);
        #pragma unroll 1
        for (int g = 0; g < ng; g++) {
            bf16x8 fa0 = nfa0, fa1 = nfa1;
            if (g + 1 < ng) {
                nfa0 = *(const bf16x8*)(xb + (long)(n0 + (g + 1) * 16 + lo) * 64 + quad * 8);
                nfa1 = *(const bf16x8*)(xb + (long)(n0 + (g + 1) * 16 + lo) * 64 + 32 + quad * 8);
            }
            f32x4 acc = zacc;
            #pragma unroll
            for (int a = 0; a < 10; a++) {
                bf16x8 b0 = *(const bf16x8*)&mypan[(2 * a) * 512 + lbase];
                bf16x8 b1 = *(const bf16x8*)&mypan[(2 * a + 1) * 512 + lbase];
                f32x4 p = __builtin_amdgcn_mfma_f32_16x16x32_bf16(fa0, b0, zacc, 0, 0, 0);
                p = __builtin_amdgcn_mfma_f32_16x16x32_bf16(fa1, b1, p, 0, 0, 0);
                float4 afv = *(const float4*)&att[a * 128 + g * 16 + quad * 4];
                acc[0] += afv.x * p[0]; acc[1] += afv.y * p[1];
                acc[2] += afv.z * p[2]; acc[3] += afv.w * p[3];
            }
            int nb = n0 + g * 16;
            #pragma unroll
            for (int r = 0; r < 4; r++)
                sc_s[(long)(nb + quad * 4 + r) * 128 + vtg * 16 + lo] = acc[r] * SK_NORM;
        }
    } else if (type == 2) {
        int vt = vp * 2 + wv;
        bf16x8 nfa0[3], nfa1[3];
        #pragma unroll
        for (int i = 0; i < 3; i++) {
            const unsigned short* xb = xpk + (size_t)(1 + i) * XPLN + (long)(n0 + lo) * 64;
            nfa0[i] = *(const bf16x8*)(xb + quad * 8);
            nfa1[i] = *(const bf16x8*)(xb + 32 + quad * 8);
        }
        #pragma unroll 1
        for (int g = 0; g < ng; g++) {
            bf16x8 fa0[3], fa1[3];
            #pragma unroll
            for (int i = 0; i < 3; i++) { fa0[i] = nfa0[i]; fa1[i] = nfa1[i]; }
            if (g + 1 < ng) {
                #pragma unroll
                for (int i = 0; i < 3; i++) {
                    const unsigned short* xb = xpk + (size_t)(1 + i) * XPLN + (long)(n0 + (g + 1) * 16 + lo) * 64;
                    nfa0[i] = *(const bf16x8*)(xb + quad * 8);
                    nfa1[i] = *(const bf16x8*)(xb + 32 + quad * 8);
                }
            }
            f32x4 acc0 = zacc, acc1 = zacc, acc2 = zacc;
            #pragma unroll
            for (int a = 0; a < 10; a++) {
                bf16x8 b0 = *(const bf16x8*)&mypan[(2 * a) * 512 + lbase];
                bf16x8 b1 = *(const bf16x8*)&mypan[(2 * a + 1) * 512 + lbase];
                float4 afv = *(const float4*)&att[a * 128 + g * 16 + quad * 4];
                f32x4 p0 = __builtin_amdgcn_mfma_f32_16x16x32_bf16(fa0[0], b0, zacc, 0, 0, 0);
                p0 = __builtin_amdgcn_mfma_f32_16x16x32_bf16(fa1[0], b1, p0, 0, 0, 0);
                acc0[0] += afv.x * p0[0]; acc0[1] += afv.y * p0[1];
                acc0[2] += afv.z * p0[2]; acc0[3] += afv.w * p0[3];
                f32x4 p1 = __builtin_amdgcn_mfma_f32_16x16x32_bf16(fa0[1], b0, zacc, 0, 0, 0);
                p1 = __builtin_amdgcn_mfma_f32_16x16x32_bf16(fa1[1], b1, p1, 0, 0, 0);
                acc1[0] += afv.x * p1[0]; acc1[1] += afv.y * p1[1];
                acc1[2] += afv.z * p1[2]; acc1[3] += afv.w * p1[3];
                f32x4 p2 = __builtin_amdgcn_mfma_f32_16x16x32_bf16(fa0[2], b0, zacc, 0, 0, 0);
                p2 = __builtin_amdgcn_mfma_f32_16x16x32_bf16(fa1[2], b1, p2, 0, 0, 0);
                acc2[0] += afv.x * p2[0]; acc2[1] += afv.y * p2[1];
                acc2[2] += afv.z * p2[2]; acc2[3] += afv.w * p2[3];
            }
            int nb = n0 + g * 16;
            #pragma unroll
            for (int r = 0; r < 4; r++) {
                long rb = (long)(nb + quad * 4 + r) * 192 + vt * 16 + lo;
                sc_v[rb]       = acc0[r] * SK_NORM;
                sc_v[rb + 64]  = acc1[r] * SK_NORM;
                sc_v[rb + 128] = acc2[r] * SK_NORM;
            }
        }
    } else {
        int vt = vp * 2 + wv;
        bf16x8 bk20 = *(const bf16x8*)&pan[wv * 1024 + lbase];
        bf16x8 bk21 = *(const bf16x8*)&pan[wv * 1024 + 512 + lbase];
        bf16x8 bk30 = *(const bf16x8*)&pan[2048 + wv * 1024 + lbase];
        bf16x8 bk31 = *(const bf16x8*)&pan[2048 + wv * 1024 + 512 + lbase];
        #pragma unroll 1
        for (int g = 0; g < ng; g++) {
            int nb = n0 + g * 16;
            const unsigned short* xb0 = xpk + (long)(nb + lo) * 64;
            bf16x8 fa00 = *(const bf16x8*)(xb0 + quad * 8);
            bf16x8 fa01 = *(const bf16x8*)(xb0 + 32 + quad * 8);
            f32x4 acc0 = __builtin_amdgcn_mfma_f32_16x16x32_bf16(fa00, bk20, zacc, 0, 0, 0);
            acc0 = __builtin_amdgcn_mfma_f32_16x16x32_bf16(fa01, bk21, acc0, 0, 0, 0);
            const unsigned short* xb1 = xpk + (size_t)1 * XPLN + (long)(nb + lo) * 64;
            bf16x8 fa10 = *(const bf16x8*)(xb1 + quad * 8);
            bf16x8 fa11 = *(const bf16x8*)(xb1 + 32 + quad * 8);
            f32x4 acc1 = __builtin_amdgcn_mfma_f32_16x16x32_bf16(fa10, bk30, zacc, 0, 0, 0);
            acc1 = __builtin_amdgcn_mfma_f32_16x16x32_bf16(fa11, bk31, acc1, 0, 0, 0);
            const unsigned short* xb2 = xpk + (size_t)2 * XPLN + (long)(nb + lo) * 64;
            bf16x8 fa20 = *(const bf16x8*)(xb2 + quad * 8);
            bf16x8 fa21 = *(const bf16x8*)(xb2 + 32 + quad * 8);
            f32x4 acc2 = __builtin_amdgcn_mfma_f32_16x16x32_bf16(fa20, bk30, zacc, 0, 0, 0);
            acc2 = __builtin_amdgcn_mfma_f32_16x16x32_bf16(fa21, bk31, acc2, 0, 0, 0);
            const unsigned short* xb3 = xpk + (size_t)3 * XPLN + (long)(nb + lo) * 64;
            bf16x8 fa30 = *(const bf16x8*)(xb3 + quad * 8);
            bf16x8 fa31 = *(const bf16x8*)(xb3 + 32 + quad * 8);
            f32x4 acc3 = __builtin_amdgcn_mfma_f32_16x16x32_bf16(fa30, bk30, zacc, 0, 0, 0);
            acc3 = __builtin_amdgcn_mfma_f32_16x16x32_bf16(fa31, bk31, acc3, 0, 0, 0);
            #pragma unroll
            for (int r = 0; r < 4; r++) {
                x4[(long)(nb + quad * 4 + r) * 64 + vt * 16 + lo] =
                    make_float4(acc0[r] * UP_NORM, acc1[r] * UP_NORM,
                                acc2[r] * UP_NORM, acc3[r] * UP_NORM);
            }
        }
    }
}

// ---------------- K3: CSR build by receiver (epk = packed {sender, edge})
__global__ __launch_bounds__(256) void k_hist(const int* __restrict__ rcv, int* __restrict__ counts) {
    int e = blockIdx.x * 256 + threadIdx.x;
    if (e < NE) atomicAdd(&counts[rcv[e]], 1);
}

__global__ __launch_bounds__(1024) void k_scan(const int* __restrict__ counts, int* __restrict__ offsets) {
    __shared__ int partial[1024];
    int t = threadIdx.x;
    const int CHUNKS = (NN + 1023) / 1024;   // 10
    int base = t * CHUNKS;
    int s = 0;
    for (int i = 0; i < CHUNKS; i++) if (base + i < NN) s += counts[base + i];
    partial[t] = s;
    __syncthreads();
    for (int d = 1; d < 1024; d *= 2) {
        int v = (t >= d) ? partial[t - d] : 0;
        __syncthreads();
        partial[t] += v;
        __syncthreads();
    }
    int excl = (t == 0) ? 0 : partial[t - 1];
    for (int i = 0; i < CHUNKS; i++) {
        if (base + i < NN) { offsets[base + i] = excl; excl += counts[base + i]; }
    }
    if (t == 1023) offsets[NN] = partial[1023];
}

__global__ __launch_bounds__(256) void k_fill(const int* __restrict__ rcv, const int* __restrict__ snd,
                                              const int* __restrict__ offsets,
                                              int* __restrict__ cursor, int2* __restrict__ epk) {
    int e = blockIdx.x * 256 + threadIdx.x;
    if (e < NE) {
        int r = rcv[e];
        int pos = atomicAdd(&cursor[r], 1);
        epk[offsets[r] + pos] = make_int2(snd[e], e);
    }
}

// ---------------- K_eprep: CSR-ordered edge streams
__global__ __launch_bounds__(256) void k_eprep(const int2* __restrict__ epk,
                                               const float4* __restrict__ ear, const float4* __restrict__ eai,
                                               const float4* __restrict__ ef,
                                               int* __restrict__ sndp,
                                               float4* __restrict__ earp, float4* __restrict__ eaip,
                                               float4* __restrict__ efp) {
    int j = blockIdx.x * 256 + threadIdx.x;
    if (j >= NE) return;
    int2 se = epk[j];
    sndp[j] = se.x;
    earp[j] = ear[se.y];
    eaip[j] = eai[se.y];
    efp[(long)j * 2]     = ef[(long)se.y * 2];
    efp[(long)j * 2 + 1] = ef[(long)se.y * 2 + 1];
}

// ---------------- K2 v4: edge MLP via MFMA — occupancy unlocked (round-10, kept).
#define HID_STRIDE 72
#define OB_STRIDE  40
#define EPB 64

__global__ __launch_bounds__(256) void k_edge_mlp(
    const float4* __restrict__ efp, const unsigned short* __restrict__ WFG,
    __hip_bfloat16* __restrict__ twp) {
    __shared__ unsigned short wfrag[20 * 512];          // 20480 B (L1-L3 only)
    __shared__ unsigned short hid[4][16 * HID_STRIDE];  //  9216 B

    int t = threadIdx.x;
    for (int i = t; i < 20 * 512 / 8; i += 256)
        ((float4*)wfrag)[i] = ((const float4*)WFG)[i];
    __syncthreads();

    int wv = t >> 6;
    int lane = t & 63;
    int lo = lane & 15;
    int quad = lane >> 4;
    int lbase = lane * 8;
    unsigned short* myhid = hid[wv];
    unsigned short* myob  = hid[wv];    // alias; safe per-wave in-order DS
    const unsigned short* W4 = WFG + 20 * 512;   // M4 frags from global/L2
    const f32x4 zacc = {0.f, 0.f, 0.f, 0.f};

    long jbase = (long)blockIdx.x * EPB + wv * 16;

    // ---- layer 1: [16x8] @ [8x64] (K padded to 32), silu ----
    bf16x8 a1 = {0, 0, 0, 0, 0, 0, 0, 0};
    if (quad == 0) {
        float4 f0 = efp[(jbase + lo) * 2];
        float4 f1 = efp[(jbase + lo) * 2 + 1];
        union { unsigned short us[8]; bf16x8 v; } pk;
        pk.us[0] = f2bf_bits(f0.x * M1_NORM); pk.us[1] = f2bf_bits(f0.y * M1_NORM);
        pk.us[2] = f2bf_bits(f0.z * M1_NORM); pk.us[3] = f2bf_bits(f0.w * M1_NORM);
        pk.us[4] = f2bf_bits(f1.x * M1_NORM); pk.us[5] = f2bf_bits(f1.y * M1_NORM);
        pk.us[6] = f2bf_bits(f1.z * M1_NORM); pk.us[7] = f2bf_bits(f1.w * M1_NORM);
        a1 = pk.v;
    }
    {
        f32x4 acc[4];
        #pragma unroll
        for (int nt = 0; nt < 4; nt++) {
            bf16x8 b = *(const bf16x8*)&wfrag[nt * 512 + lbase];
            acc[nt] = __builtin_amdgcn_mfma_f32_16x16x32_bf16(a1, b, zacc, 0, 0, 0);
        }
        #pragma unroll
        for (int nt = 0; nt < 4; nt++)
            #pragma unroll
            for (int r = 0; r < 4; r++)
                myhid[(quad * 4 + r) * HID_STRIDE + nt * 16 + lo] = f2bf_bits(siluf(acc[nt][r]));
    }

    // ---- layers 2,3: [16x64] @ [64x64] /8, silu ----
    #pragma unroll
    for (int L = 0; L < 2; L++) {
        int fb = 4 + L * 8;
        bf16x8 a0 = *(const bf16x8*)&myhid[lo * HID_STRIDE + quad * 8];
        bf16x8 a1v = *(const bf16x8*)&myhid[lo * HID_STRIDE + 32 + quad * 8];
        f32x4 acc[4];
        #pragma unroll
        for (int nt = 0; nt < 4; nt++) {
            bf16x8 b0 = *(const bf16x8*)&wfrag[(fb + nt * 2) * 512 + lbase];
            bf16x8 b1 = *(const bf16x8*)&wfrag[(fb + nt * 2 + 1) * 512 + lbase];
            acc[nt] = __builtin_amdgcn_mfma_f32_16x16x32_bf16(a0, b0, zacc, 0, 0, 0);
            acc[nt] = __builtin_amdgcn_mfma_f32_16x16x32_bf16(a1v, b1, acc[nt], 0, 0, 0);
        }
        #pragma unroll
        for (int nt = 0; nt < 4; nt++)
            #pragma unroll
            for (int r = 0; r < 4; r++)
                myhid[(quad * 4 + r) * HID_STRIDE + nt * 16 + lo] = f2bf_bits(siluf(acc[nt][r] * 0.125f));
    }

    // ---- layer 4: [16x64] @ [64x256] /8, pair output, 16B LDS-shuffled stores ----
    {
        bf16x8 a0 = *(const bf16x8*)&myhid[lo * HID_STRIDE + quad * 8];
        bf16x8 a1v = *(const bf16x8*)&myhid[lo * HID_STRIDE + 32 + quad * 8];
        int sedge = lane >> 2, sch = lane & 3;
        #pragma unroll
        for (int rd = 0; rd < 8; rd++) {
            f32x4 acc2[2];
            #pragma unroll
            for (int p = 0; p < 2; p++) {
                int tt = (rd < 4) ? (p * 4 + rd) : (8 + p * 4 + (rd - 4));
                bf16x8 b0 = *(const bf16x8*)(W4 + (tt * 2) * 512 + lbase);
                bf16x8 b1 = *(const bf16x8*)(W4 + (tt * 2 + 1) * 512 + lbase);
                acc2[p] = __builtin_amdgcn_mfma_f32_16x16x32_bf16(a0, b0, zacc, 0, 0, 0);
                acc2[p] = __builtin_amdgcn_mfma_f32_16x16x32_bf16(a1v, b1, acc2[p], 0, 0, 0);
            }
            #pragma unroll
            for (int p = 0; p < 2; p++)
                #pragma unroll
                for (int r = 0; r < 4; r++)
                    myob[(quad * 4 + r) * OB_STRIDE + 2 * lo + p] = f2bf_bits(acc2[p][r] * 0.125f);
            bf16x8 vv = *(const bf16x8*)&myob[sedge * OB_STRIDE + sch * 8];
            *(bf16x8*)(twp + (jbase + sedge) * 256 + rd * 32 + sch * 8) = vv;
        }
    }
}

// ---------------- K4 v7: conv_tp + segment sum -> msgF.
// Round-11 post-mortem: packed x4 + CB2=8 regressed (VGPR 52->92, occ 30->18%,
// 67us) -- the batch-depth doubling cost more TLP than the gather packing
// saved. v7 DECOUPLES: keep the single dwordx4 x-gather (one address chain,
// one contiguous 1KB wave-region), revert CB2 to 4 (buffer VGPRs ~56 ->
// occupancy back to ~30%). Accumulation order unchanged -> bit-identical msgF.
#define NPB 4
#define CB2 4
__global__ __launch_bounds__(256) void k_conv(
    const int* __restrict__ offsets, const int* __restrict__ sndp,
    const float4* __restrict__ earp, const float4* __restrict__ eaip,
    const float4* __restrict__ x4,
    const __hip_bfloat16* __restrict__ twp,
    unsigned short* __restrict__ msgF) {
    __shared__ unsigned short stg[NPB][1024];
    int t = threadIdx.x;
    int wv = t >> 6;
    int u = t & 63;
    int n = blockIdx.x * NPB + wv;
    int beg = offsets[n], end = offsets[n + 1];
    int deg = end - beg;
    int sreg = (u < deg) ? sndp[beg + u] : 0;   // lane-parallel senders
    const int tsel0 = 2 * u, tsel1 = 128 + 2 * u;
    float a0r = 0.f, a1r = 0.f, a2r = 0.f, a3r = 0.f;
    float a0i = 0.f, a1i = 0.f, a2i = 0.f, a3i = 0.f;
    float c0r = 0.f, c1r = 0.f, c2r = 0.f, c3r = 0.f;
    float c0i = 0.f, c1i = 0.f, c2i = 0.f, c3i = 0.f;

    for (int jb = beg; jb < end; jb += CB2) {
        unsigned int t0[CB2], t1[CB2];
        float4 xv[CB2], yr[CB2], yi[CB2];
        #pragma unroll
        for (int p = 0; p < CB2; p++) {
            int j = jb + p;
            int jc = (j < end) ? j : (end - 1);
            int le = jc - beg;
            int s = (le < 64) ? __shfl(sreg, le) : sndp[jc];
            yr[p] = earp[jc];
            yi[p] = eaip[jc];
            xv[p] = x4[(long)s * 64 + u];
            bool valid = (j < end);
            t0[p] = valid ? *(const unsigned int*)(twp + (long)jc * 256 + tsel0) : 0u;
            t1[p] = valid ? *(const unsigned int*)(twp + (long)jc * 256 + tsel1) : 0u;
        }
        #pragma unroll
        for (int p = 0; p < CB2; p++) {
            float wA = bflo(t0[p]), wB = bfhi(t0[p]);
            float xa = xv[p].x * wA, xb = xv[p].x * wB;
            a0r += xa * yr[p].x; a1r += xb * yr[p].y; a2r += xb * yr[p].z; a3r += xb * yr[p].w;
            a0i += xa * yi[p].x; a1i += xb * yi[p].y; a2i += xb * yi[p].z; a3i += xb * yi[p].w;
            float wC = bflo(t1[p]), wDs = bfhi(t1[p]) * INV3;
            float dr = xv[p].y * yr[p].y + xv[p].z * yr[p].z + xv[p].w * yr[p].w;
            float di = xv[p].y * yi[p].y + xv[p].z * yi[p].z + xv[p].w * yi[p].w;
            c0r += dr * wDs; c0i += di * wDs;
            float ycr = yr[p].x * wC, yci = yi[p].x * wC;
            c1r += xv[p].y * ycr; c2r += xv[p].z * ycr; c3r += xv[p].w * ycr;
            c1i += xv[p].y * yci; c2i += xv[p].z * yci; c3i += xv[p].w * yci;
        }
    }

    unsigned short* sg = stg[wv];
    sg[u]       = f2bf_bits(a0r);
    sg[128 + u] = f2bf_bits(a0i);
    sg[256 + u] = f2bf_bits(a1r);
    sg[384 + u] = f2bf_bits(a2r);
    sg[512 + u] = f2bf_bits(a3r);
    sg[640 + u] = f2bf_bits(a1i);
    sg[768 + u] = f2bf_bits(a2i);
    sg[896 + u] = f2bf_bits(a3i);
    sg[64 + u]  = f2bf_bits(c0r);
    sg[192 + u] = f2bf_bits(c0i);
    sg[320 + u] = f2bf_bits(c1r);
    sg[448 + u] = f2bf_bits(c2r);
    sg[576 + u] = f2bf_bits(c3r);
    sg[704 + u] = f2bf_bits(c1i);
    sg[832 + u] = f2bf_bits(c2i);
    sg[960 + u] = f2bf_bits(c3i);
    __syncthreads();

    #pragma unroll
    for (int rep = 0; rep < 2; rep++) {
        int job = rep * 256 + t;
        int m = job >> 7, c = job & 127;
        int nm = blockIdx.x * NPB + m;
        int g = nm >> 4, lo = nm & 15;
        bf16x8 vv = *(const bf16x8*)&stg[m][c * 8];
        *(bf16x8*)(msgF + (size_t)g * 16384 + (c >> 2) * 512 + lo * 32 + (c & 3) * 8) = vv;
    }
}

// ---------------- K5 v2: MFMA lin + skip + gate, fragment-major (unchanged).
#define SV_STRIDE 129
#define VV_STRIDE 65

__global__ __launch_bounds__(256, 3) void k_lin(
    const unsigned short* __restrict__ msgF,
    const float* __restrict__ sc_s, const float* __restrict__ sc_v,
    const unsigned short* __restrict__ WLF,
    float* __restrict__ out) {
    __shared__ char smem[49152];
    unsigned short* wfrag = (unsigned short*)smem;
    float* sval = (float*)smem;                       // aliased after barrier
    float* vval = (float*)(smem + 2 * 16 * SV_STRIDE * 4);

    int t = threadIdx.x;
    for (int i = t; i < 48 * 512 / 8; i += 256)
        ((float4*)wfrag)[i] = ((const float4*)WLF)[i];
    __syncthreads();

    int wv = t >> 6;
    int lane = t & 63;
    int lo = lane & 15;
    int quad = lane >> 4;
    int lbase = lane * 8;
    int aoff_lane = lo * 32 + quad * 8;
    const f32x4 zacc = {0.f, 0.f, 0.f, 0.f};

    long g = blockIdx.x;
    long nbase = g * 16;
    const unsigned short* agbase = msgF + (size_t)g * 16384;

    f32x4 accs[10];
    #pragma unroll
    for (int q = 0; q < 10; q++) {
        int tau = wv + q * 4;
        int cblk, fb;
        if (tau < 16) {
            int ri = tau >> 3, vt = tau & 7;
            cblk = ri; fb = vt * 4;
        } else {
            int tp = tau - 16;
            int ri = tp / 12, rem = tp % 12;
            int i = rem >> 2, vt = rem & 3;
            cblk = 2 + ri * 3 + i; fb = 32 + vt * 4;
        }
        f32x4 acc = zacc;
        #pragma unroll
        for (int ks = 0; ks < 4; ks++) {
            bf16x8 a = *(const bf16x8*)(agbase + (cblk * 4 + ks) * 512 + aoff_lane);
            bf16x8 b = *(const bf16x8*)&wfrag[(fb + ks) * 512 + lbase];
            acc = __builtin_amdgcn_mfma_f32_16x16x32_bf16(a, b, acc, 0, 0, 0);
        }
        accs[q] = acc;
    }
    __syncthreads();   // all weight LDS reads complete before aliasing

    #pragma unroll
    for (int q = 0; q < 10; q++) {
        int tau = wv + q * 4;
        if (tau < 16) {
            int ri = tau >> 3, vt = tau & 7;
            int cidx = (ri * 16) * SV_STRIDE + vt * 16 + lo;
            #pragma unroll
            for (int r = 0; r < 4; r++)
                sval[cidx + (quad * 4 + r) * SV_STRIDE] = accs[q][r] * LIN_NORM;
        } else {
            int tp = tau - 16;
            int ri = tp / 12, rem = tp % 12;
            int i = rem >> 2, vt = rem & 3;
            int cidx = ((ri * 3 + i) * 16) * VV_STRIDE + vt * 16 + lo;
            #pragma unroll
            for (int r = 0; r < 4; r++)
                vval[cidx + (quad * 4 + r) * VV_STRIDE] = accs[q][r] * LIN_NORM;
        }
    }
    __syncthreads();

    #pragma unroll 1
    for (int j = 0; j < 16; j++) {
        int c = t;
        long gn = nbase + j;
        float re, im;
        if (c < 64) {
            float sr = sval[(0 * 16 + j) * SV_STRIDE + c] + sc_s[gn * 128 + c];
            float si = sval[(1 * 16 + j) * SV_STRIDE + c];
            re = siluf(sr); im = siluf(si);
        } else {
            int rem = c - 64;
            int v = rem / 3;
            int i = rem - v * 3;
            float gr = siluf(sval[(0 * 16 + j) * SV_STRIDE + 64 + v] + sc_s[gn * 128 + 64 + v]);
            float gi = siluf(sval[(1 * 16 + j) * SV_STRIDE + 64 + v]);
            float lr = vval[((0 * 3 + i) * 16 + j) * VV_STRIDE + v] + sc_v[gn * 192 + i * 64 + v];
            float li = vval[((1 * 3 + i) * 16 + j) * VV_STRIDE + v];
            re = lr * gr; im = li * gi;
        }
        ((float2*)out)[gn * 256 + c] = make_float2(re, im);
    }
}

extern "C" void kernel_launch(void* const* d_in, const int* in_sizes, int n_in,
                              void* d_out, int out_size, void* d_ws, size_t ws_size,
                              hipStream_t stream) {
    const float* node_attrs = (const float*)d_in[0];
    const float* node_feats = (const float*)d_in[1];
    const float* ear        = (const float*)d_in[2];
    const float* eai        = (const float*)d_in[3];
    const float* edge_feats = (const float*)d_in[4];
    const float* W_up0      = (const float*)d_in[5];
    const float* W_up1      = (const float*)d_in[6];
    const float* M1         = (const float*)d_in[7];
    const float* M2         = (const float*)d_in[8];
    const float* M3         = (const float*)d_in[9];
    const float* M4         = (const float*)d_in[10];
    const float* W_lin_s    = (const float*)d_in[11];
    const float* W_lin_v    = (const float*)d_in[12];
    const float* W_sk_s     = (const float*)d_in[13];
    const float* W_sk_v     = (const float*)d_in[14];
    const int*   ei         = (const int*)d_in[15];

    char* ws = (char*)d_ws;
    size_t o_x4  = 0;                                   // packed x: NN*64 float4 (10.24MB)
    size_t o_scs = o_x4 + (size_t)NN * 64 * 16;
    size_t o_scv = o_scs + (size_t)NN * 128 * 4;
    size_t o_tw  = o_scv + (size_t)NN * 192 * 4;
    size_t o_cnt = o_tw  + (size_t)NE * 256 * 2;
    size_t o_cur = o_cnt + (size_t)NN * 4;
    size_t o_ofs = o_cur + (size_t)NN * 4;
    size_t o_epk = o_ofs + (size_t)(NN + 1) * 4 + 60;
    size_t o_snd = o_epk + (size_t)NE * 8;
    size_t o_rcv = o_snd + (size_t)NE * 4;
    size_t o_flg = o_rcv + (size_t)NE * 4;
    size_t o_msg = o_flg + 64;
    size_t o_wnf = o_msg + (size_t)NN * 1024 * 2;
    size_t o_snp = o_wnf + 262144;
    size_t o_erp = o_snp + (size_t)NE * 4;
    size_t o_eip = o_erp + (size_t)NE * 16;
    size_t o_efp = o_eip + (size_t)NE * 16;
    size_t o_wfg = o_efp + (size_t)NE * 32;
    size_t o_wlf = o_wfg + (size_t)52 * 512 * 2;
    size_t o_xpk = o_wlf + (size_t)48 * 512 * 2;
    size_t o_atp = o_xpk + (size_t)4 * NN * 64 * 2;

    float4* x4 = (float4*)(ws + o_x4);
    float* sc_s = (float*)(ws + o_scs);
    float* sc_v = (float*)(ws + o_scv);
    __hip_bfloat16* twp = (__hip_bfloat16*)(ws + o_tw);
    int* counts  = (int*)(ws + o_cnt);
    int* cursor  = (int*)(ws + o_cur);
    int* offsets = (int*)(ws + o_ofs);
    int2* epk    = (int2*)(ws + o_epk);
    int* snd     = (int*)(ws + o_snd);
    int* rcv     = (int*)(ws + o_rcv);
    int* flag    = (int*)(ws + o_flg);
    unsigned short* msgF = (unsigned short*)(ws + o_msg);
    unsigned short* WNF = (unsigned short*)(ws + o_wnf);
    int*    sndp = (int*)(ws + o_snp);
    float4* earp = (float4*)(ws + o_erp);
    float4* eaip = (float4*)(ws + o_eip);
    float4* efp  = (float4*)(ws + o_efp);
    unsigned short* WFG = (unsigned short*)(ws + o_wfg);
    unsigned short* WLF = (unsigned short*)(ws + o_wlf);
    unsigned short* xpk = (unsigned short*)(ws + o_xpk);
    float* attrsP = (float*)(ws + o_atp);

    hipMemsetAsync(ws + o_cnt, 0, (size_t)NN * 8, stream);

    dim3 b256(256), b1024(1024), b128(128);
    k_detect<<<dim3(1), b256, 0, stream>>>(ei, flag);
    k_cvt   <<<dim3((NE + 255) / 256), b256, 0, stream>>>(ei, flag, snd, rcv);
    k_hist<<<dim3((NE + 255) / 256), b256, 0, stream>>>(rcv, counts);
    k_scan<<<dim3(1), b1024, 0, stream>>>(counts, offsets);
    k_fill<<<dim3((NE + 255) / 256), b256, 0, stream>>>(rcv, snd, offsets, cursor, epk);
    k_eprep<<<dim3((NE + 255) / 256), b256, 0, stream>>>(epk, (const float4*)ear, (const float4*)eai,
                                                         (const float4*)edge_feats,
                                                         sndp, earp, eaip, efp);
    k_wprepN<<<dim3(512), b256, 0, stream>>>(W_sk_s, W_sk_v, W_up0, W_up1, WNF);
    k_wprep2<<<dim3(200), b256, 0, stream>>>(M1, M2, M3, M4, W_lin_s, W_lin_v, WFG, WLF);
    k_xprep <<<dim3((4 * NN * 64 + 10 * NN + 255) / 256), b256, 0, stream>>>(node_attrs, node_feats, xpk, attrsP);
    k_node  <<<dim3(KNODE_GRID), b128, 0, stream>>>(xpk, attrsP, WNF, sc_s, sc_v, x4);
    k_edge_mlp<<<dim3(NE / EPB), b256, 0, stream>>>(efp, WFG, twp);
    k_conv<<<dim3(NN / NPB), b256, 0, stream>>>(offsets, sndp, earp, eaip, x4, twp, msgF);
    k_lin <<<dim3(NGRP), b256, 0, stream>>>(msgF, sc_s, sc_v, WLF, (float*)d_out);
}

// Round 13
// 252.273 us; speedup vs baseline: 1.1442x; 1.0599x over previous
//
#include <hip/hip_runtime.h>
#include <hip/hip_bf16.h>

#define NN 10000
#define NE 160000
#define NGRP 625            // NN/16
#define XPLN 640000         // NN*64 elems per plane

#define SK_NORM   0.039528470752104741f   // 1/sqrt(640)
#define UP_NORM   0.125f                  // 1/8
#define M1_NORM   0.35355339059327373f    // 1/sqrt(8)
#define INV3      0.5773502691896258f
#define LIN_NORM  0.0027621358640099516f  // 1/sqrt(128)/32

__device__ __forceinline__ float siluf(float x) { return x / (1.0f + __expf(-x)); }

__device__ __forceinline__ unsigned short f2bf_bits(float x) {
    union { __hip_bfloat16 h; unsigned short u; } cv;
    cv.h = __float2bfloat16(x);
    return cv.u;
}
__device__ __forceinline__ float bflo(unsigned int w) { return __uint_as_float(w << 16); }
__device__ __forceinline__ float bfhi(unsigned int w) { return __uint_as_float(w & 0xffff0000u); }

typedef short bf16x8 __attribute__((ext_vector_type(8)));
typedef float f32x4  __attribute__((ext_vector_type(4)));

// ---------------- K_cvt_hist: dtype-detect (per-block, L2-hit) + extract + histogram.
// Merges old k_detect/k_cvt/k_hist: one pass, 2 fewer launches, no rcv re-read.
__global__ __launch_bounds__(256) void k_cvt_hist(const int* __restrict__ ei32,
                                                  int* __restrict__ snd, int* __restrict__ rcv,
                                                  int* __restrict__ counts) {
    __shared__ int sflag;
    int t = threadIdx.x;
    if (t == 0) sflag = 0;
    __syncthreads();
    int z = 0;
    for (int i = t; i < 1024; i += 256)
        if (ei32[2 * i + 1] == 0) z++;
    if (z) atomicAdd(&sflag, z);
    __syncthreads();
    bool is64 = (sflag >= 512);
    int e = blockIdx.x * 256 + t;
    if (e >= NE) return;
    int s, r;
    if (is64) {
        const long long* e64 = (const long long*)ei32;
        s = (int)e64[e];
        r = (int)e64[NE + e];
    } else {
        s = ei32[e];
        r = ei32[NE + e];
    }
    snd[e] = s;
    rcv[e] = r;
    atomicAdd(&counts[r], 1);
}

__global__ __launch_bounds__(1024) void k_scan(const int* __restrict__ counts, int* __restrict__ offsets) {
    __shared__ int partial[1024];
    int t = threadIdx.x;
    const int CHUNKS = (NN + 1023) / 1024;   // 10
    int base = t * CHUNKS;
    int s = 0;
    for (int i = 0; i < CHUNKS; i++) if (base + i < NN) s += counts[base + i];
    partial[t] = s;
    __syncthreads();
    for (int d = 1; d < 1024; d *= 2) {
        int v = (t >= d) ? partial[t - d] : 0;
        __syncthreads();
        partial[t] += v;
        __syncthreads();
    }
    int excl = (t == 0) ? 0 : partial[t - 1];
    for (int i = 0; i < CHUNKS; i++) {
        if (base + i < NN) { offsets[base + i] = excl; excl += counts[base + i]; }
    }
    if (t == 1023) offsets[NN] = partial[1023];
}

// ---------------- K_fill_eprep: direct CSR scatter of all edge streams.
// Merges old k_fill+k_eprep: each thread knows its slot j = offsets[r]+pos,
// so epk is never materialized (saves its 2.6MB round-trip + 1 launch).
// Coalesced reads, scattered 16B writes (was gathered reads, coalesced writes
// -- same randomness, one less pass). Slot order within a node remains
// atomic-nondeterministic, exactly as before.
__global__ __launch_bounds__(256) void k_fill_eprep(
    const int* __restrict__ rcv, const int* __restrict__ snd,
    const int* __restrict__ offsets, int* __restrict__ cursor,
    const float4* __restrict__ ear, const float4* __restrict__ eai,
    const float4* __restrict__ ef,
    int* __restrict__ sndp,
    float4* __restrict__ earp, float4* __restrict__ eaip,
    float4* __restrict__ efp) {
    int e = blockIdx.x * 256 + threadIdx.x;
    if (e >= NE) return;
    int r = rcv[e];
    int pos = atomicAdd(&cursor[r], 1);
    int j = offsets[r] + pos;
    sndp[j] = snd[e];
    earp[j] = ear[e];
    eaip[j] = eai[e];
    efp[(long)j * 2]     = ef[(long)e * 2];
    efp[(long)j * 2 + 1] = ef[(long)e * 2 + 1];
}

// ---------------- K_prep_all: WNF + WFG/WLF + xpk/attrsP in ONE kernel.
// Merges old k_wprepN/k_wprep2/k_xprep (pure elementwise, disjoint ranges).
#define PREP_N1 131072                       // WNF
#define PREP_N2 (PREP_N1 + 100 * 512)        // +WFG/WLF = 182272
#define PREP_N3 (PREP_N2 + 4 * NN * 64)      // +xpk = 2742272
#define PREP_N4 (PREP_N3 + 10 * NN)          // +attrsP = 2842272

__global__ __launch_bounds__(256) void k_prep_all(
    const float* __restrict__ Wsk_s, const float* __restrict__ Wsk_v,
    const float* __restrict__ Wu0, const float* __restrict__ Wu1,
    const float* __restrict__ M1, const float* __restrict__ M2,
    const float* __restrict__ M3, const float* __restrict__ M4,
    const float* __restrict__ W_lin_s, const float* __restrict__ W_lin_v,
    const float* __restrict__ node_attrs, const float* __restrict__ node_feats,
    unsigned short* __restrict__ WNF, unsigned short* __restrict__ WFG,
    unsigned short* __restrict__ WLF,
    unsigned short* __restrict__ xpk, float* __restrict__ attrsP) {
    int gidx = blockIdx.x * 256 + threadIdx.x;
    if (gidx < PREP_N1) {
        int idx = gidx;
        float val;
        if (idx < 81920) {
            int p = idx / 10240, r = idx % 10240;
            int kc = r >> 9, l8 = r & 511;
            int lane = l8 >> 3, j = l8 & 7, quad = lane >> 4, lo = lane & 15;
            int a = kc >> 1, u = (kc & 1) * 32 + quad * 8 + j;
            val = Wsk_s[(u * 10 + a) * 128 + p * 16 + lo];
        } else if (idx < 122880) {
            int rel = idx - 81920;
            int p = rel / 10240, r = rel % 10240;
            int kc = r >> 9, l8 = r & 511;
            int lane = l8 >> 3, j = l8 & 7, quad = lane >> 4, lo = lane & 15;
            int a = kc >> 1, u = (kc & 1) * 32 + quad * 8 + j;
            val = Wsk_v[(u * 10 + a) * 64 + p * 16 + lo];
        } else if (idx < 126976) {
            int rel = idx - 122880;
            int p = rel >> 10, r = rel & 1023;
            int kc = r >> 9, l8 = r & 511;
            int lane = l8 >> 3, j = l8 & 7, quad = lane >> 4, lo = lane & 15;
            int u = kc * 32 + quad * 8 + j;
            val = Wu0[u * 64 + p * 16 + lo];
        } else {
            int rel = idx - 126976;
            int p = rel >> 10, r = rel & 1023;
            int kc = r >> 9, l8 = r & 511;
            int lane = l8 >> 3, j = l8 & 7, quad = lane >> 4, lo = lane & 15;
            int u = kc * 32 + quad * 8 + j;
            val = Wu1[u * 64 + p * 16 + lo];
        }
        WNF[idx] = f2bf_bits(val);
        return;
    }
    if (gidx < PREP_N2) {
        int idx = gidx - PREP_N1;
        if (idx < 52 * 512) {
            int f = idx >> 9, r = idx & 511;
            int lane = r >> 3, j = r & 7;
            int quad = lane >> 4, lo = lane & 15;
            float val;
            if (f < 4) {
                int n = f * 16 + lo, k = quad * 8 + j;
                val = (k < 8) ? M1[k * 64 + n] : 0.f;
            } else if (f < 12) {
                int g2 = f - 4, nt = g2 >> 1, half = g2 & 1;
                int n = nt * 16 + lo, k = half * 32 + quad * 8 + j;
                val = M2[k * 64 + n];
            } else if (f < 20) {
                int g3 = f - 12, nt = g3 >> 1, half = g3 & 1;
                int n = nt * 16 + lo, k = half * 32 + quad * 8 + j;
                val = M3[k * 64 + n];
            } else {
                int g4 = f - 20, tt = g4 >> 1, half = g4 & 1;
                int n = tt * 16 + lo, k = half * 32 + quad * 8 + j;
                val = M4[k * 256 + n];
            }
            WFG[idx] = f2bf_bits(val);
        } else {
            int rel = idx - 52 * 512;
            int f = rel >> 9, r = rel & 511;
            int lane = r >> 3, j = r & 7;
            int quad = lane >> 4, lo = lane & 15;
            float val;
            if (f < 32) {
                int vt = f >> 2, ks = f & 3;
                val = W_lin_s[(ks * 32 + quad * 8 + j) * 128 + vt * 16 + lo];
            } else {
                int f2 = f - 32;
                int vt = f2 >> 2, ks = f2 & 3;
                val = W_lin_v[(ks * 32 + quad * 8 + j) * 64 + vt * 16 + lo];
            }
            WLF[rel] = f2bf_bits(val);
        }
        return;
    }
    if (gidx < PREP_N3) {
        int idx = gidx - PREP_N2;
        int n = idx >> 8, c = idx & 255;
        int plane = c >> 6, u = c & 63;
        float v = (plane == 0) ? node_feats[(long)n * 256 + u]
                               : node_feats[(long)n * 256 + 64 + u * 3 + (plane - 1)];
        xpk[(size_t)plane * XPLN + (long)n * 64 + u] = f2bf_bits(v);
        return;
    }
    if (gidx < PREP_N4) {
        int i2 = gidx - PREP_N3;
        int a = i2 / NN, n = i2 - a * NN;
        attrsP[i2] = node_attrs[(long)n * 10 + a];
    }
}

// ---------------- K_node v6: type-3 writes PACKED x4 (float4 per channel; kept).
#define G0 8
#define NB0 79
#define G2 4
#define NB2 157
#define G3 16
#define NB3 40
#define KNODE_GRID (4*NB0 + 2*NB2 + 2*NB3)   // 710

__global__ __launch_bounds__(128) void k_node(
    const unsigned short* __restrict__ xpk, const float* __restrict__ attrsP,
    const unsigned short* __restrict__ WNF,
    float* __restrict__ sc_s, float* __restrict__ sc_v,
    float4* __restrict__ x4) {
    __shared__ unsigned short pan[2 * 10240];
    __shared__ float att[10 * 128];

    int t = threadIdx.x;
    int bid = blockIdx.x;
    int type, vp, chunk;
    if (bid < 4 * NB0)                 { type = 0; vp = bid / NB0; chunk = bid % NB0; }
    else if (bid < 4 * NB0 + 2 * NB2)  { int r = bid - 4 * NB0; type = 2; vp = r / NB2; chunk = r % NB2; }
    else                               { int r = bid - 4 * NB0 - 2 * NB2; type = 3; vp = r / NB3; chunk = r % NB3; }
    int G = (type == 0) ? G0 : (type == 2 ? G2 : G3);
    int g0 = chunk * G;
    int ng = NGRP - g0; if (ng > G) ng = G;
    int n0 = g0 * 16;

    int psrc, pcnt;
    if (type == 0)      { psrc = vp * 2 * 10240;           pcnt = 20480; }
    else if (type == 2) { psrc = 81920 + vp * 2 * 10240;   pcnt = 20480; }
    else                { psrc = 122880 + vp * 2 * 1024;   pcnt = 2048;  }
    for (int i = t; i < pcnt / 8; i += 128)
        ((float4*)pan)[i] = ((const float4*)(WNF + psrc))[i];
    if (type == 3) {
        for (int i = t; i < 2048 / 8; i += 128)
            ((float4*)(pan + 2048))[i] = ((const float4*)(WNF + 126976 + vp * 2 * 1024))[i];
    }
    if (type <= 2) {
        int cnt = ng * 16;
        #pragma unroll
        for (int k = 0; k < 10; k++) {
            int i = k * 128 + t;
            int nl = t;
            if (nl < cnt) att[i] = attrsP[k * NN + n0 + nl];
        }
    }
    __syncthreads();

    int wv = t >> 6, lane = t & 63, lo = lane & 15, quad = lane >> 4;
    int lbase = lane * 8;
    const f32x4 zacc = {0.f, 0.f, 0.f, 0.f};
    const unsigned short* mypan = pan + wv * 10240;

    if (type == 0) {
        int vtg = vp * 2 + wv;
        const unsigned short* xb = xpk;
        bf16x8 nfa0 = *(const bf16x8*)(xb + (long)(n0 + lo) * 64 + quad * 8);
        bf16x8 nfa1 = *(const bf16x8*)(xb + (long)(n0 + lo) * 64 + 32 + quad * 8);
        #pragma unroll 1
        for (int g = 0; g < ng; g++) {
            bf16x8 fa0 = nfa0, fa1 = nfa1;
            if (g + 1 < ng) {
                nfa0 = *(const bf16x8*)(xb + (long)(n0 + (g + 1) * 16 + lo) * 64 + quad * 8);
                nfa1 = *(const bf16x8*)(xb + (long)(n0 + (g + 1) * 16 + lo) * 64 + 32 + quad * 8);
            }
            f32x4 acc = zacc;
            #pragma unroll
            for (int a = 0; a < 10; a++) {
                bf16x8 b0 = *(const bf16x8*)&mypan[(2 * a) * 512 + lbase];
                bf16x8 b1 = *(const bf16x8*)&mypan[(2 * a + 1) * 512 + lbase];
                f32x4 p = __builtin_amdgcn_mfma_f32_16x16x32_bf16(fa0, b0, zacc, 0, 0, 0);
                p = __builtin_amdgcn_mfma_f32_16x16x32_bf16(fa1, b1, p, 0, 0, 0);
                float4 afv = *(const float4*)&att[a * 128 + g * 16 + quad * 4];
                acc[0] += afv.x * p[0]; acc[1] += afv.y * p[1];
                acc[2] += afv.z * p[2]; acc[3] += afv.w * p[3];
            }
            int nb = n0 + g * 16;
            #pragma unroll
            for (int r = 0; r < 4; r++)
                sc_s[(long)(nb + quad * 4 + r) * 128 + vtg * 16 + lo] = acc[r] * SK_NORM;
        }
    } else if (type == 2) {
        int vt = vp * 2 + wv;
        bf16x8 nfa0[3], nfa1[3];
        #pragma unroll
        for (int i = 0; i < 3; i++) {
            const unsigned short* xb = xpk + (size_t)(1 + i) * XPLN + (long)(n0 + lo) * 64;
            nfa0[i] = *(const bf16x8*)(xb + quad * 8);
            nfa1[i] = *(const bf16x8*)(xb + 32 + quad * 8);
        }
        #pragma unroll 1
        for (int g = 0; g < ng; g++) {
            bf16x8 fa0[3], fa1[3];
            #pragma unroll
            for (int i = 0; i < 3; i++) { fa0[i] = nfa0[i]; fa1[i] = nfa1[i]; }
            if (g + 1 < ng) {
                #pragma unroll
                for (int i = 0; i < 3; i++) {
                    const unsigned short* xb = xpk + (size_t)(1 + i) * XPLN + (long)(n0 + (g + 1) * 16 + lo) * 64;
                    nfa0[i] = *(const bf16x8*)(xb + quad * 8);
                    nfa1[i] = *(const bf16x8*)(xb + 32 + quad * 8);
                }
            }
            f32x4 acc0 = zacc, acc1 = zacc, acc2 = zacc;
            #pragma unroll
            for (int a = 0; a < 10; a++) {
                bf16x8 b0 = *(const bf16x8*)&mypan[(2 * a) * 512 + lbase];
                bf16x8 b1 = *(const bf16x8*)&mypan[(2 * a + 1) * 512 + lbase];
                float4 afv = *(const float4*)&att[a * 128 + g * 16 + quad * 4];
                f32x4 p0 = __builtin_amdgcn_mfma_f32_16x16x32_bf16(fa0[0], b0, zacc, 0, 0, 0);
                p0 = __builtin_amdgcn_mfma_f32_16x16x32_bf16(fa1[0], b1, p0, 0, 0, 0);
                acc0[0] += afv.x * p0[0]; acc0[1] += afv.y * p0[1];
                acc0[2] += afv.z * p0[2]; acc0[3] += afv.w * p0[3];
                f32x4 p1 = __builtin_amdgcn_mfma_f32_16x16x32_bf16(fa0[1], b0, zacc, 0, 0, 0);
                p1 = __builtin_amdgcn_mfma_f32_16x16x32_bf16(fa1[1], b1, p1, 0, 0, 0);
                acc1[0] += afv.x * p1[0]; acc1[1] += afv.y * p1[1];
                acc1[2] += afv.z * p1[2]; acc1[3] += afv.w * p1[3];
                f32x4 p2 = __builtin_amdgcn_mfma_f32_16x16x32_bf16(fa0[2], b0, zacc, 0, 0, 0);
                p2 = __builtin_amdgcn_mfma_f32_16x16x32_bf16(fa1[2], b1, p2, 0, 0, 0);
                acc2[0] += afv.x * p2[0]; acc2[1] += afv.y * p2[1];
                acc2[2] += afv.z * p2[2]; acc2[3] += afv.w * p2[3];
            }
            int nb = n0 + g * 16;
            #pragma unroll
            for (int r = 0; r < 4; r++) {
                long rb = (long)(nb + quad * 4 + r) * 192 + vt * 16 + lo;
                sc_v[rb]       = acc0[r] * SK_NORM;
                sc_v[rb + 64]  = acc1[r] * SK_NORM;
                sc_v[rb + 128] = acc2[r] * SK_NORM;
            }
        }
    } else {
        int vt = vp * 2 + wv;
        bf16x8 bk20 = *(const bf16x8*)&pan[wv * 1024 + lbase];
        bf16x8 bk21 = *(const bf16x8*)&pan[wv * 1024 + 512 + lbase];
        bf16x8 bk30 = *(const bf16x8*)&pan[2048 + wv * 1024 + lbase];
        bf16x8 bk31 = *(const bf16x8*)&pan[2048 + wv * 1024 + 512 + lbase];
        #pragma unroll 1
        for (int g = 0; g < ng; g++) {
            int nb = n0 + g * 16;
            const unsigned short* xb0 = xpk + (long)(nb + lo) * 64;
            bf16x8 fa00 = *(const bf16x8*)(xb0 + quad * 8);
            bf16x8 fa01 = *(const bf16x8*)(xb0 + 32 + quad * 8);
            f32x4 acc0 = __builtin_amdgcn_mfma_f32_16x16x32_bf16(fa00, bk20, zacc, 0, 0, 0);
            acc0 = __builtin_amdgcn_mfma_f32_16x16x32_bf16(fa01, bk21, acc0, 0, 0, 0);
            const unsigned short* xb1 = xpk + (size_t)1 * XPLN + (long)(nb + lo) * 64;
            bf16x8 fa10 = *(const bf16x8*)(xb1 + quad * 8);
            bf16x8 fa11 = *(const bf16x8*)(xb1 + 32 + quad * 8);
            f32x4 acc1 = __builtin_amdgcn_mfma_f32_16x16x32_bf16(fa10, bk30, zacc, 0, 0, 0);
            acc1 = __builtin_amdgcn_mfma_f32_16x16x32_bf16(fa11, bk31, acc1, 0, 0, 0);
            const unsigned short* xb2 = xpk + (size_t)2 * XPLN + (long)(nb + lo) * 64;
            bf16x8 fa20 = *(const bf16x8*)(xb2 + quad * 8);
            bf16x8 fa21 = *(const bf16x8*)(xb2 + 32 + quad * 8);
            f32x4 acc2 = __builtin_amdgcn_mfma_f32_16x16x32_bf16(fa20, bk30, zacc, 0, 0, 0);
            acc2 = __builtin_amdgcn_mfma_f32_16x16x32_bf16(fa21, bk31, acc2, 0, 0, 0);
            const unsigned short* xb3 = xpk + (size_t)3 * XPLN + (long)(nb + lo) * 64;
            bf16x8 fa30 = *(const bf16x8*)(xb3 + quad * 8);
            bf16x8 fa31 = *(const bf16x8*)(xb3 + 32 + quad * 8);
            f32x4 acc3 = __builtin_amdgcn_mfma_f32_16x16x32_bf16(fa30, bk30, zacc, 0, 0, 0);
            acc3 = __builtin_amdgcn_mfma_f32_16x16x32_bf16(fa31, bk31, acc3, 0, 0, 0);
            #pragma unroll
            for (int r = 0; r < 4; r++) {
                x4[(long)(nb + quad * 4 + r) * 64 + vt * 16 + lo] =
                    make_float4(acc0[r] * UP_NORM, acc1[r] * UP_NORM,
                                acc2[r] * UP_NORM, acc3[r] * UP_NORM);
            }
        }
    }
}

// ---------------- K2 v4: edge MLP via MFMA — occupancy unlocked (round-10, kept).
#define HID_STRIDE 72
#define OB_STRIDE  40
#define EPB 64

__global__ __launch_bounds__(256) void k_edge_mlp(
    const float4* __restrict__ efp, const unsigned short* __restrict__ WFG,
    __hip_bfloat16* __restrict__ twp) {
    __shared__ unsigned short wfrag[20 * 512];          // 20480 B (L1-L3 only)
    __shared__ unsigned short hid[4][16 * HID_STRIDE];  //  9216 B

    int t = threadIdx.x;
    for (int i = t; i < 20 * 512 / 8; i += 256)
        ((float4*)wfrag)[i] = ((const float4*)WFG)[i];
    __syncthreads();

    int wv = t >> 6;
    int lane = t & 63;
    int lo = lane & 15;
    int quad = lane >> 4;
    int lbase = lane * 8;
    unsigned short* myhid = hid[wv];
    unsigned short* myob  = hid[wv];    // alias; safe per-wave in-order DS
    const unsigned short* W4 = WFG + 20 * 512;   // M4 frags from global/L2
    const f32x4 zacc = {0.f, 0.f, 0.f, 0.f};

    long jbase = (long)blockIdx.x * EPB + wv * 16;

    // ---- layer 1: [16x8] @ [8x64] (K padded to 32), silu ----
    bf16x8 a1 = {0, 0, 0, 0, 0, 0, 0, 0};
    if (quad == 0) {
        float4 f0 = efp[(jbase + lo) * 2];
        float4 f1 = efp[(jbase + lo) * 2 + 1];
        union { unsigned short us[8]; bf16x8 v; } pk;
        pk.us[0] = f2bf_bits(f0.x * M1_NORM); pk.us[1] = f2bf_bits(f0.y * M1_NORM);
        pk.us[2] = f2bf_bits(f0.z * M1_NORM); pk.us[3] = f2bf_bits(f0.w * M1_NORM);
        pk.us[4] = f2bf_bits(f1.x * M1_NORM); pk.us[5] = f2bf_bits(f1.y * M1_NORM);
        pk.us[6] = f2bf_bits(f1.z * M1_NORM); pk.us[7] = f2bf_bits(f1.w * M1_NORM);
        a1 = pk.v;
    }
    {
        f32x4 acc[4];
        #pragma unroll
        for (int nt = 0; nt < 4; nt++) {
            bf16x8 b = *(const bf16x8*)&wfrag[nt * 512 + lbase];
            acc[nt] = __builtin_amdgcn_mfma_f32_16x16x32_bf16(a1, b, zacc, 0, 0, 0);
        }
        #pragma unroll
        for (int nt = 0; nt < 4; nt++)
            #pragma unroll
            for (int r = 0; r < 4; r++)
                myhid[(quad * 4 + r) * HID_STRIDE + nt * 16 + lo] = f2bf_bits(siluf(acc[nt][r]));
    }

    // ---- layers 2,3: [16x64] @ [64x64] /8, silu ----
    #pragma unroll
    for (int L = 0; L < 2; L++) {
        int fb = 4 + L * 8;
        bf16x8 a0 = *(const bf16x8*)&myhid[lo * HID_STRIDE + quad * 8];
        bf16x8 a1v = *(const bf16x8*)&myhid[lo * HID_STRIDE + 32 + quad * 8];
        f32x4 acc[4];
        #pragma unroll
        for (int nt = 0; nt < 4; nt++) {
            bf16x8 b0 = *(const bf16x8*)&wfrag[(fb + nt * 2) * 512 + lbase];
            bf16x8 b1 = *(const bf16x8*)&wfrag[(fb + nt * 2 + 1) * 512 + lbase];
            acc[nt] = __builtin_amdgcn_mfma_f32_16x16x32_bf16(a0, b0, zacc, 0, 0, 0);
            acc[nt] = __builtin_amdgcn_mfma_f32_16x16x32_bf16(a1v, b1, acc[nt], 0, 0, 0);
        }
        #pragma unroll
        for (int nt = 0; nt < 4; nt++)
            #pragma unroll
            for (int r = 0; r < 4; r++)
                myhid[(quad * 4 + r) * HID_STRIDE + nt * 16 + lo] = f2bf_bits(siluf(acc[nt][r] * 0.125f));
    }

    // ---- layer 4: [16x64] @ [64x256] /8, pair output, 16B LDS-shuffled stores ----
    {
        bf16x8 a0 = *(const bf16x8*)&myhid[lo * HID_STRIDE + quad * 8];
        bf16x8 a1v = *(const bf16x8*)&myhid[lo * HID_STRIDE + 32 + quad * 8];
        int sedge = lane >> 2, sch = lane & 3;
        #pragma unroll
        for (int rd = 0; rd < 8; rd++) {
            f32x4 acc2[2];
            #pragma unroll
            for (int p = 0; p < 2; p++) {
                int tt = (rd < 4) ? (p * 4 + rd) : (8 + p * 4 + (rd - 4));
                bf16x8 b0 = *(const bf16x8*)(W4 + (tt * 2) * 512 + lbase);
                bf16x8 b1 = *(const bf16x8*)(W4 + (tt * 2 + 1) * 512 + lbase);
                acc2[p] = __builtin_amdgcn_mfma_f32_16x16x32_bf16(a0, b0, zacc, 0, 0, 0);
                acc2[p] = __builtin_amdgcn_mfma_f32_16x16x32_bf16(a1v, b1, acc2[p], 0, 0, 0);
            }
            #pragma unroll
            for (int p = 0; p < 2; p++)
                #pragma unroll
                for (int r = 0; r < 4; r++)
                    myob[(quad * 4 + r) * OB_STRIDE + 2 * lo + p] = f2bf_bits(acc2[p][r] * 0.125f);
            bf16x8 vv = *(const bf16x8*)&myob[sedge * OB_STRIDE + sch * 8];
            *(bf16x8*)(twp + (jbase + sedge) * 256 + rd * 32 + sch * 8) = vv;
        }
    }
}

// ---------------- K4 v7: conv_tp + segment sum -> msgF (round-12, kept).
// Structural floor ~45us for this decomposition: 130MB HBM (82MB twp re-read
// inherent while MLP/conv are separate; fusion measured 2.7x worse) in a mixed
// stream+gather pattern topping out ~2.9TB/s. Seven variants all 44-47us.
#define NPB 4
#define CB2 4
__global__ __launch_bounds__(256) void k_conv(
    const int* __restrict__ offsets, const int* __restrict__ sndp,
    const float4* __restrict__ earp, const float4* __restrict__ eaip,
    const float4* __restrict__ x4,
    const __hip_bfloat16* __restrict__ twp,
    unsigned short* __restrict__ msgF) {
    __shared__ unsigned short stg[NPB][1024];
    int t = threadIdx.x;
    int wv = t >> 6;
    int u = t & 63;
    int n = blockIdx.x * NPB + wv;
    int beg = offsets[n], end = offsets[n + 1];
    int deg = end - beg;
    int sreg = (u < deg) ? sndp[beg + u] : 0;   // lane-parallel senders
    const int tsel0 = 2 * u, tsel1 = 128 + 2 * u;
    float a0r = 0.f, a1r = 0.f, a2r = 0.f, a3r = 0.f;
    float a0i = 0.f, a1i = 0.f, a2i = 0.f, a3i = 0.f;
    float c0r = 0.f, c1r = 0.f, c2r = 0.f, c3r = 0.f;
    float c0i = 0.f, c1i = 0.f, c2i = 0.f, c3i = 0.f;

    for (int jb = beg; jb < end; jb += CB2) {
        unsigned int t0[CB2], t1[CB2];
        float4 xv[CB2], yr[CB2], yi[CB2];
        #pragma unroll
        for (int p = 0; p < CB2; p++) {
            int j = jb + p;
            int jc = (j < end) ? j : (end - 1);
            int le = jc - beg;
            int s = (le < 64) ? __shfl(sreg, le) : sndp[jc];
            yr[p] = earp[jc];
            yi[p] = eaip[jc];
            xv[p] = x4[(long)s * 64 + u];
            bool valid = (j < end);
            t0[p] = valid ? *(const unsigned int*)(twp + (long)jc * 256 + tsel0) : 0u;
            t1[p] = valid ? *(const unsigned int*)(twp + (long)jc * 256 + tsel1) : 0u;
        }
        #pragma unroll
        for (int p = 0; p < CB2; p++) {
            float wA = bflo(t0[p]), wB = bfhi(t0[p]);
            float xa = xv[p].x * wA, xb = xv[p].x * wB;
            a0r += xa * yr[p].x; a1r += xb * yr[p].y; a2r += xb * yr[p].z; a3r += xb * yr[p].w;
            a0i += xa * yi[p].x; a1i += xb * yi[p].y; a2i += xb * yi[p].z; a3i += xb * yi[p].w;
            float wC = bflo(t1[p]), wDs = bfhi(t1[p]) * INV3;
            float dr = xv[p].y * yr[p].y + xv[p].z * yr[p].z + xv[p].w * yr[p].w;
            float di = xv[p].y * yi[p].y + xv[p].z * yi[p].z + xv[p].w * yi[p].w;
            c0r += dr * wDs; c0i += di * wDs;
            float ycr = yr[p].x * wC, yci = yi[p].x * wC;
            c1r += xv[p].y * ycr; c2r += xv[p].z * ycr; c3r += xv[p].w * ycr;
            c1i += xv[p].y * yci; c2i += xv[p].z * yci; c3i += xv[p].w * yci;
        }
    }

    unsigned short* sg = stg[wv];
    sg[u]       = f2bf_bits(a0r);
    sg[128 + u] = f2bf_bits(a0i);
    sg[256 + u] = f2bf_bits(a1r);
    sg[384 + u] = f2bf_bits(a2r);
    sg[512 + u] = f2bf_bits(a3r);
    sg[640 + u] = f2bf_bits(a1i);
    sg[768 + u] = f2bf_bits(a2i);
    sg[896 + u] = f2bf_bits(a3i);
    sg[64 + u]  = f2bf_bits(c0r);
    sg[192 + u] = f2bf_bits(c0i);
    sg[320 + u] = f2bf_bits(c1r);
    sg[448 + u] = f2bf_bits(c2r);
    sg[576 + u] = f2bf_bits(c3r);
    sg[704 + u] = f2bf_bits(c1i);
    sg[832 + u] = f2bf_bits(c2i);
    sg[960 + u] = f2bf_bits(c3i);
    __syncthreads();

    #pragma unroll
    for (int rep = 0; rep < 2; rep++) {
        int job = rep * 256 + t;
        int m = job >> 7, c = job & 127;
        int nm = blockIdx.x * NPB + m;
        int g = nm >> 4, lo = nm & 15;
        bf16x8 vv = *(const bf16x8*)&stg[m][c * 8];
        *(bf16x8*)(msgF + (size_t)g * 16384 + (c >> 2) * 512 + lo * 32 + (c & 3) * 8) = vv;
    }
}

// ---------------- K5 v2: MFMA lin + skip + gate, fragment-major (unchanged).
#define SV_STRIDE 129
#define VV_STRIDE 65

__global__ __launch_bounds__(256, 3) void k_lin(
    const unsigned short* __restrict__ msgF,
    const float* __restrict__ sc_s, const float* __restrict__ sc_v,
    const unsigned short* __restrict__ WLF,
    float* __restrict__ out) {
    __shared__ char smem[49152];
    unsigned short* wfrag = (unsigned short*)smem;
    float* sval = (float*)smem;                       // aliased after barrier
    float* vval = (float*)(smem + 2 * 16 * SV_STRIDE * 4);

    int t = threadIdx.x;
    for (int i = t; i < 48 * 512 / 8; i += 256)
        ((float4*)wfrag)[i] = ((const float4*)WLF)[i];
    __syncthreads();

    int wv = t >> 6;
    int lane = t & 63;
    int lo = lane & 15;
    int quad = lane >> 4;
    int lbase = lane * 8;
    int aoff_lane = lo * 32 + quad * 8;
    const f32x4 zacc = {0.f, 0.f, 0.f, 0.f};

    long g = blockIdx.x;
    long nbase = g * 16;
    const unsigned short* agbase = msgF + (size_t)g * 16384;

    f32x4 accs[10];
    #pragma unroll
    for (int q = 0; q < 10; q++) {
        int tau = wv + q * 4;
        int cblk, fb;
        if (tau < 16) {
            int ri = tau >> 3, vt = tau & 7;
            cblk = ri; fb = vt * 4;
        } else {
            int tp = tau - 16;
            int ri = tp / 12, rem = tp % 12;
            int i = rem >> 2, vt = rem & 3;
            cblk = 2 + ri * 3 + i; fb = 32 + vt * 4;
        }
        f32x4 acc = zacc;
        #pragma unroll
        for (int ks = 0; ks < 4; ks++) {
            bf16x8 a = *(const bf16x8*)(agbase + (cblk * 4 + ks) * 512 + aoff_lane);
            bf16x8 b = *(const bf16x8*)&wfrag[(fb + ks) * 512 + lbase];
            acc = __builtin_amdgcn_mfma_f32_16x16x32_bf16(a, b, acc, 0, 0, 0);
        }
        accs[q] = acc;
    }
    __syncthreads();   // all weight LDS reads complete before aliasing

    #pragma unroll
    for (int q = 0; q < 10; q++) {
        int tau = wv + q * 4;
        if (tau < 16) {
            int ri = tau >> 3, vt = tau & 7;
            int cidx = (ri * 16) * SV_STRIDE + vt * 16 + lo;
            #pragma unroll
            for (int r = 0; r < 4; r++)
                sval[cidx + (quad * 4 + r) * SV_STRIDE] = accs[q][r] * LIN_NORM;
        } else {
            int tp = tau - 16;
            int ri = tp / 12, rem = tp % 12;
            int i = rem >> 2, vt = rem & 3;
            int cidx = ((ri * 3 + i) * 16) * VV_STRIDE + vt * 16 + lo;
            #pragma unroll
            for (int r = 0; r < 4; r++)
                vval[cidx + (quad * 4 + r) * VV_STRIDE] = accs[q][r] * LIN_NORM;
        }
    }
    __syncthreads();

    #pragma unroll 1
    for (int j = 0; j < 16; j++) {
        int c = t;
        long gn = nbase + j;
        float re, im;
        if (c < 64) {
            float sr = sval[(0 * 16 + j) * SV_STRIDE + c] + sc_s[gn * 128 + c];
            float si = sval[(1 * 16 + j) * SV_STRIDE + c];
            re = siluf(sr); im = siluf(si);
        } else {
            int rem = c - 64;
            int v = rem / 3;
            int i = rem - v * 3;
            float gr = siluf(sval[(0 * 16 + j) * SV_STRIDE + 64 + v] + sc_s[gn * 128 + 64 + v]);
            float gi = siluf(sval[(1 * 16 + j) * SV_STRIDE + 64 + v]);
            float lr = vval[((0 * 3 + i) * 16 + j) * VV_STRIDE + v] + sc_v[gn * 192 + i * 64 + v];
            float li = vval[((1 * 3 + i) * 16 + j) * VV_STRIDE + v];
            re = lr * gr; im = li * gi;
        }
        ((float2*)out)[gn * 256 + c] = make_float2(re, im);
    }
}

extern "C" void kernel_launch(void* const* d_in, const int* in_sizes, int n_in,
                              void* d_out, int out_size, void* d_ws, size_t ws_size,
                              hipStream_t stream) {
    const float* node_attrs = (const float*)d_in[0];
    const float* node_feats = (const float*)d_in[1];
    const float* ear        = (const float*)d_in[2];
    const float* eai        = (const float*)d_in[3];
    const float* edge_feats = (const float*)d_in[4];
    const float* W_up0      = (const float*)d_in[5];
    const float* W_up1      = (const float*)d_in[6];
    const float* M1         = (const float*)d_in[7];
    const float* M2         = (const float*)d_in[8];
    const float* M3         = (const float*)d_in[9];
    const float* M4         = (const float*)d_in[10];
    const float* W_lin_s    = (const float*)d_in[11];
    const float* W_lin_v    = (const float*)d_in[12];
    const float* W_sk_s     = (const float*)d_in[13];
    const float* W_sk_v     = (const float*)d_in[14];
    const int*   ei         = (const int*)d_in[15];

    char* ws = (char*)d_ws;
    size_t o_x4  = 0;                                   // packed x: NN*64 float4 (10.24MB)
    size_t o_scs = o_x4 + (size_t)NN * 64 * 16;
    size_t o_scv = o_scs + (size_t)NN * 128 * 4;
    size_t o_tw  = o_scv + (size_t)NN * 192 * 4;
    size_t o_cnt = o_tw  + (size_t)NE * 256 * 2;
    size_t o_cur = o_cnt + (size_t)NN * 4;
    size_t o_ofs = o_cur + (size_t)NN * 4;
    size_t o_epk = o_ofs + (size_t)(NN + 1) * 4 + 60;   // (slot retained, unused)
    size_t o_snd = o_epk + (size_t)NE * 8;
    size_t o_rcv = o_snd + (size_t)NE * 4;
    size_t o_flg = o_rcv + (size_t)NE * 4;
    size_t o_msg = o_flg + 64;
    size_t o_wnf = o_msg + (size_t)NN * 1024 * 2;
    size_t o_snp = o_wnf + 262144;
    size_t o_erp = o_snp + (size_t)NE * 4;
    size_t o_eip = o_erp + (size_t)NE * 16;
    size_t o_efp = o_eip + (size_t)NE * 16;
    size_t o_wfg = o_efp + (size_t)NE * 32;
    size_t o_wlf = o_wfg + (size_t)52 * 512 * 2;
    size_t o_xpk = o_wlf + (size_t)48 * 512 * 2;
    size_t o_atp = o_xpk + (size_t)4 * NN * 64 * 2;

    float4* x4 = (float4*)(ws + o_x4);
    float* sc_s = (float*)(ws + o_scs);
    float* sc_v = (float*)(ws + o_scv);
    __hip_bfloat16* twp = (__hip_bfloat16*)(ws + o_tw);
    int* counts  = (int*)(ws + o_cnt);
    int* cursor  = (int*)(ws + o_cur);
    int* offsets = (int*)(ws + o_ofs);
    int* snd     = (int*)(ws + o_snd);
    int* rcv     = (int*)(ws + o_rcv);
    unsigned short* msgF = (unsigned short*)(ws + o_msg);
    unsigned short* WNF = (unsigned short*)(ws + o_wnf);
    int*    sndp = (int*)(ws + o_snp);
    float4* earp = (float4*)(ws + o_erp);
    float4* eaip = (float4*)(ws + o_eip);
    float4* efp  = (float4*)(ws + o_efp);
    unsigned short* WFG = (unsigned short*)(ws + o_wfg);
    unsigned short* WLF = (unsigned short*)(ws + o_wlf);
    unsigned short* xpk = (unsigned short*)(ws + o_xpk);
    float* attrsP = (float*)(ws + o_atp);

    hipMemsetAsync(ws + o_cnt, 0, (size_t)NN * 8, stream);

    dim3 b256(256), b1024(1024), b128(128);
    k_cvt_hist<<<dim3((NE + 255) / 256), b256, 0, stream>>>(ei, snd, rcv, counts);
    k_scan<<<dim3(1), b1024, 0, stream>>>(counts, offsets);
    k_fill_eprep<<<dim3((NE + 255) / 256), b256, 0, stream>>>(
        rcv, snd, offsets, cursor,
        (const float4*)ear, (const float4*)eai, (const float4*)edge_feats,
        sndp, earp, eaip, efp);
    k_prep_all<<<dim3((PREP_N4 + 255) / 256), b256, 0, stream>>>(
        W_sk_s, W_sk_v, W_up0, W_up1, M1, M2, M3, M4, W_lin_s, W_lin_v,
        node_attrs, node_feats, WNF, WFG, WLF, xpk, attrsP);
    k_node  <<<dim3(KNODE_GRID), b128, 0, stream>>>(xpk, attrsP, WNF, sc_s, sc_v, x4);
    k_edge_mlp<<<dim3(NE / EPB), b256, 0, stream>>>(efp, WFG, twp);
    k_conv<<<dim3(NN / NPB), b256, 0, stream>>>(offsets, sndp, earp, eaip, x4, twp, msgF);
    k_lin <<<dim3(NGRP), b256, 0, stream>>>(msgF, sc_s, sc_v, WLF, (float*)d_out);
}